// Round 11
// baseline (3523.439 us; speedup 1.0000x reference)
//
#include <hip/hip_runtime.h>
#include <hip/hip_bf16.h>
#include <math.h>

#define NN 20000
#define NE 640000
#define H  128
#define RB 50
#define NL 6

typedef unsigned short u16;
typedef __attribute__((ext_vector_type(8))) short short8v;
typedef __attribute__((ext_vector_type(4))) float f32x4;

// feature permutation: col c -> slot (c&15)*8 + (c>>4)  (8 MFMA-cols per lane contiguous)
__device__ __forceinline__ u16 f2b(float v) {
  unsigned x = __float_as_uint(v);
  unsigned r = (x + 0x7FFFu + ((x >> 16) & 1u)) >> 16;
  return (u16)r;
}
__device__ __forceinline__ float b2f(u16 u) {
  return __uint_as_float(((unsigned int)u) << 16);
}

// ---------------- sort machinery ----------------
__global__ void k_zero_i32(int* __restrict__ p, int n) {
  int i = blockIdx.x * blockDim.x + threadIdx.x;
  if (i < n) p[i] = 0;
}
__global__ void k_hist(const int* __restrict__ ei, int* __restrict__ counts) {
  int e = blockIdx.x * blockDim.x + threadIdx.x;
  if (e < NE) atomicAdd(&counts[ei[NE + e]], 1);
}
__global__ void k_scan(const int* __restrict__ counts, int* __restrict__ cursor) {
  __shared__ int buf[1024];
  __shared__ int carry;
  int tid = threadIdx.x;
  if (tid == 0) carry = 0;
  __syncthreads();
  for (int base = 0; base < NN; base += 1024) {
    int i = base + tid;
    int v = (i < NN) ? counts[i] : 0;
    buf[tid] = v;
    __syncthreads();
    for (int off = 1; off < 1024; off <<= 1) {
      int t = (tid >= off) ? buf[tid - off] : 0;
      __syncthreads();
      buf[tid] += t;
      __syncthreads();
    }
    int incl = buf[tid];
    int excl = incl - v + carry;
    if (i < NN) cursor[i] = excl;
    __syncthreads();
    if (tid == 1023) carry += incl;
    __syncthreads();
  }
}
__global__ void k_place(const int* __restrict__ ei, int* __restrict__ cursor,
                        int* __restrict__ perm) {
  int e = blockIdx.x * blockDim.x + threadIdx.x;
  if (e < NE) {
    int d = ei[NE + e];
    int p = atomicAdd(&cursor[d], 1);
    perm[p] = e;
  }
}

// ---------------- edge precompute ----------------
__global__ void k_edge(const int* __restrict__ ei, const int* __restrict__ perm,
                       const float* __restrict__ pos, const float* __restrict__ means,
                       const float* __restrict__ betas,
                       int* __restrict__ srcS, int* __restrict__ dstS,
                       float* __restrict__ CS, u16* __restrict__ attrG) {
  int p = blockIdx.x * 256 + threadIdx.x;
  if (p >= NE) return;
  int e = perm[p];
  int s = ei[e], t = ei[NE + e];
  srcS[p] = s; dstS[p] = t;
  float dx = pos[3*s]   - pos[3*t];
  float dy = pos[3*s+1] - pos[3*t+1];
  float dz = pos[3*s+2] - pos[3*t+2];
  float d = sqrtf(dx*dx + dy*dy + dz*dz);
  float C = 0.5f * (cosf(d * 0.628318530717958647692f) + 1.0f);
  if (d >= 5.0f) C = 0.f;
  CS[p] = C;
  float tv = expf(-d);
  u16* row = attrG + (size_t)p * 64;
  for (int k = 0; k < RB; ++k) {
    float diff = tv - means[k];
    row[k] = f2b(C * expf(-betas[k] * diff * diff));
  }
  for (int k = RB; k < 64; ++k) row[k] = 0;
}

// ---------------- weight pre-transpose/convert to bf16 ----------------
__global__ void k_prepw(const float* __restrict__ npW, const float* __restrict__ W1,
                        const float* __restrict__ W2, u16* __restrict__ npWt,
                        u16* __restrict__ w1tA, u16* __restrict__ w2tA) {
  int i = blockIdx.x * 256 + threadIdx.x;
  if (i < 8192) {
    int n = i >> 6, k = i & 63;
    npWt[i] = (k < RB) ? f2b(npW[k * H + n]) : (u16)0;
  } else if (i < 57344) {
    int j = i - 8192;
    int l = j >> 13, r = j & 8191;
    int n = r >> 6, k = r & 63;
    w1tA[j] = (k < RB) ? f2b(W1[(size_t)l * RB * H + (size_t)k * H + n]) : (u16)0;
  } else if (i < 161792) {
    int j = i - 57344;
    int l = j / 17408, r = j % 17408;
    int n = r / 136, k = r % 136;
    w2tA[j] = (k < H) ? f2b(W2[(size_t)l * H * H + (size_t)k * H + n]) : (u16)0;
  }
}

// x f32 natural; xn bf16 PERMUTED; agg zero-init
__global__ void k_embed(const int* __restrict__ z, const float* __restrict__ emb,
                        const float* __restrict__ nemb,
                        float* __restrict__ x, u16* __restrict__ xnb,
                        float* __restrict__ aggz) {
  int i = blockIdx.x * blockDim.x + threadIdx.x;
  if (i >= NN * H) return;
  int n = i >> 7, c = i & (H - 1);
  long o = (long)z[n] * H + c;
  x[i] = emb[o];
  xnb[(size_t)n * H + ((c & 15) * 8 + (c >> 4))] = f2b(nemb[o]);
  aggz[i] = 0.f;
}

// ---------------- combine: x = [x||agg]@cW + cb;  h0 = x@l1W0 (bf16, permuted) ----------------
__global__ __launch_bounds__(256) void k_combine(
    const float* __restrict__ xb, float* __restrict__ ag,
    const float* __restrict__ cW, const float* __restrict__ cb,
    const float* __restrict__ l1W0, float* __restrict__ xout,
    u16* __restrict__ hb)
{
  __shared__ float sX[32][132];
  __shared__ float sG[32][132];
  int tid = threadIdx.x;
  int n0 = blockIdx.x * 32;
  #pragma unroll
  for (int j = 0; j < 4; ++j) {
    int f4 = tid + j * 256;
    int r = f4 >> 5, c4 = f4 & 31;
    *(float4*)&sX[r][c4 * 4] = *(const float4*)&xb[(size_t)(n0 + r) * H + c4 * 4];
    float4 gv = *(const float4*)&ag[(size_t)(n0 + r) * H + c4 * 4];  // permuted storage
    int clo = 4 * (c4 & 1), chi = c4 >> 1;   // slot i=4c4+t -> col (4(c4&1)+t)*16 + (c4>>1)
    sG[r][(clo + 0) * 16 + chi] = gv.x;
    sG[r][(clo + 1) * 16 + chi] = gv.y;
    sG[r][(clo + 2) * 16 + chi] = gv.z;
    sG[r][(clo + 3) * 16 + chi] = gv.w;
    *(float4*)&ag[(size_t)(n0 + r) * H + c4 * 4] = make_float4(0.f, 0.f, 0.f, 0.f);
  }
  __syncthreads();
  int g = tid >> 5;
  int c0 = (tid & 31) * 4;
  int eb = g * 4;
  float acc[4][4];
  #pragma unroll
  for (int i = 0; i < 4; ++i)
    for (int j = 0; j < 4; ++j) acc[i][j] = 0.f;
  for (int k = 0; k < H; ++k) {
    float4 wv = *(const float4*)&cW[(size_t)k * H + c0];
    #pragma unroll
    for (int i = 0; i < 4; ++i) {
      float a = sX[eb + i][k];
      acc[i][0] += a * wv.x; acc[i][1] += a * wv.y;
      acc[i][2] += a * wv.z; acc[i][3] += a * wv.w;
    }
  }
  for (int k = 0; k < H; ++k) {
    float4 wv = *(const float4*)&cW[(size_t)(H + k) * H + c0];
    #pragma unroll
    for (int i = 0; i < 4; ++i) {
      float a = sG[eb + i][k];
      acc[i][0] += a * wv.x; acc[i][1] += a * wv.y;
      acc[i][2] += a * wv.z; acc[i][3] += a * wv.w;
    }
  }
  float4 bv = *(const float4*)&cb[c0];
  __syncthreads();
  #pragma unroll
  for (int i = 0; i < 4; ++i) {
    int n = n0 + eb + i;
    float o0 = acc[i][0] + bv.x, o1 = acc[i][1] + bv.y;
    float o2 = acc[i][2] + bv.z, o3 = acc[i][3] + bv.w;
    *(float4*)&xout[(size_t)n * H + c0] = make_float4(o0, o1, o2, o3);
    sX[eb + i][c0] = o0; sX[eb + i][c0+1] = o1;
    sX[eb + i][c0+2] = o2; sX[eb + i][c0+3] = o3;
  }
  __syncthreads();
  #pragma unroll
  for (int i = 0; i < 4; ++i)
    for (int j = 0; j < 4; ++j) acc[i][j] = 0.f;
  for (int k = 0; k < H; ++k) {
    float4 wv = *(const float4*)&l1W0[(size_t)k * H + c0];
    #pragma unroll
    for (int i = 0; i < 4; ++i) {
      float a = sX[eb + i][k];
      acc[i][0] += a * wv.x; acc[i][1] += a * wv.y;
      acc[i][2] += a * wv.z; acc[i][3] += a * wv.w;
    }
  }
  int pbase = (c0 & 15) * 8 + (c0 >> 4);
  #pragma unroll
  for (int i = 0; i < 4; ++i) {
    int n = n0 + eb + i;
    #pragma unroll
    for (int j = 0; j < 4; ++j)
      hb[(size_t)n * H + pbase + 8 * j] = f2b(acc[i][j]);
  }
}

// ---------------- fused lin2+lin (+next-layer lin1) ----------------
// x = xin + silu(A@W2+b2)@W3 + b3 -> xout;  A (=agg, permuted) re-zeroed; hb permuted
__global__ __launch_bounds__(256) void k_gemmF2(
    float* __restrict__ A, const float* __restrict__ W2,
    const float* __restrict__ b2, const float* __restrict__ W3,
    const float* __restrict__ b3, const float* __restrict__ xin,
    float* __restrict__ xout, const float* __restrict__ l1Wn,
    u16* __restrict__ hb)
{
  __shared__ float sA[32][132];
  __shared__ float sT[32][132];
  int tid = threadIdx.x;
  int n0 = blockIdx.x * 32;
  #pragma unroll
  for (int j = 0; j < 4; ++j) {
    int f4 = tid + j * 256;
    int r = f4 >> 5, c4 = f4 & 31;
    float4 gv = *(const float4*)&A[(size_t)(n0 + r) * H + c4 * 4];  // permuted storage
    int clo = 4 * (c4 & 1), chi = c4 >> 1;
    sA[r][(clo + 0) * 16 + chi] = gv.x;
    sA[r][(clo + 1) * 16 + chi] = gv.y;
    sA[r][(clo + 2) * 16 + chi] = gv.z;
    sA[r][(clo + 3) * 16 + chi] = gv.w;
    *(float4*)&A[(size_t)(n0 + r) * H + c4 * 4] = make_float4(0.f, 0.f, 0.f, 0.f);
  }
  __syncthreads();
  int g = tid >> 5;
  int c0 = (tid & 31) * 4;
  int eb = g * 4;
  float acc[4][4];
  #pragma unroll
  for (int i = 0; i < 4; ++i)
    for (int j = 0; j < 4; ++j) acc[i][j] = 0.f;
  for (int k = 0; k < H; ++k) {
    float4 wv = *(const float4*)&W2[(size_t)k * H + c0];
    #pragma unroll
    for (int i = 0; i < 4; ++i) {
      float a = sA[eb + i][k];
      acc[i][0] += a * wv.x; acc[i][1] += a * wv.y;
      acc[i][2] += a * wv.z; acc[i][3] += a * wv.w;
    }
  }
  float4 bv2 = *(const float4*)&b2[c0];
  #pragma unroll
  for (int i = 0; i < 4; ++i) {
    float t0 = acc[i][0] + bv2.x, t1 = acc[i][1] + bv2.y;
    float t2 = acc[i][2] + bv2.z, t3 = acc[i][3] + bv2.w;
    sT[eb + i][c0 + 0] = t0 / (1.f + __expf(-t0));
    sT[eb + i][c0 + 1] = t1 / (1.f + __expf(-t1));
    sT[eb + i][c0 + 2] = t2 / (1.f + __expf(-t2));
    sT[eb + i][c0 + 3] = t3 / (1.f + __expf(-t3));
  }
  __syncthreads();
  #pragma unroll
  for (int i = 0; i < 4; ++i)
    for (int j = 0; j < 4; ++j) acc[i][j] = 0.f;
  for (int k = 0; k < H; ++k) {
    float4 wv = *(const float4*)&W3[(size_t)k * H + c0];
    #pragma unroll
    for (int i = 0; i < 4; ++i) {
      float a = sT[eb + i][k];
      acc[i][0] += a * wv.x; acc[i][1] += a * wv.y;
      acc[i][2] += a * wv.z; acc[i][3] += a * wv.w;
    }
  }
  float4 bv3 = *(const float4*)&b3[c0];
  #pragma unroll
  for (int i = 0; i < 4; ++i) {
    int n = n0 + eb + i;
    float4 xv = *(const float4*)&xin[(size_t)n * H + c0];
    float o0 = xv.x + acc[i][0] + bv3.x, o1 = xv.y + acc[i][1] + bv3.y;
    float o2 = xv.z + acc[i][2] + bv3.z, o3 = xv.w + acc[i][3] + bv3.w;
    *(float4*)&xout[(size_t)n * H + c0] = make_float4(o0, o1, o2, o3);
    sA[eb + i][c0] = o0; sA[eb + i][c0+1] = o1;
    sA[eb + i][c0+2] = o2; sA[eb + i][c0+3] = o3;
  }
  if (l1Wn) {
    __syncthreads();
    #pragma unroll
    for (int i = 0; i < 4; ++i)
      for (int j = 0; j < 4; ++j) acc[i][j] = 0.f;
    for (int k = 0; k < H; ++k) {
      float4 wv = *(const float4*)&l1Wn[(size_t)k * H + c0];
      #pragma unroll
      for (int i = 0; i < 4; ++i) {
        float a = sA[eb + i][k];
        acc[i][0] += a * wv.x; acc[i][1] += a * wv.y;
        acc[i][2] += a * wv.z; acc[i][3] += a * wv.w;
      }
    }
    int pbase = (c0 & 15) * 8 + (c0 >> 4);
    #pragma unroll
    for (int i = 0; i < 4; ++i) {
      int n = n0 + eb + i;
      #pragma unroll
      for (int j = 0; j < 4; ++j)
        hb[(size_t)n * H + pbase + 8 * j] = f2b(acc[i][j]);
    }
  }
}

// ---------------- LDS-free MFMA neighbor embedding ----------------
__global__ __launch_bounds__(256) void k_nbr2(
    const int* __restrict__ srcS, const int* __restrict__ dstS,
    const float* __restrict__ CS, const u16* __restrict__ attrG,
    const u16* __restrict__ npWt, const float* __restrict__ npb,
    const u16* __restrict__ xnb, float* __restrict__ agg)
{
  int tid = threadIdx.x;
  int lane = tid & 63, wv = tid >> 6;
  int r16 = lane & 15, g4 = lane >> 4;
  long base = (long)blockIdx.x * 128 + wv * 32;
  int e32 = lane & 31;
  int srcR = srcS[base + e32];
  int dstR = dstS[base + e32];
  float CR = CS[base + e32];
  // band A h gather (permuted xnb: lane's 8 cols contiguous)
  short8v hvA[4];
  #pragma unroll
  for (int r = 0; r < 4; ++r) {
    int s = __shfl(srcR, g4 * 4 + r, 64);
    hvA[r] = *(const short8v*)&xnb[(size_t)s * H + r16 * 8];
  }
  f32x4 acc[2][8];
  #pragma unroll
  for (int rl = 0; rl < 2; ++rl)
    for (int ct = 0; ct < 8; ++ct) acc[rl][ct] = (f32x4){0.f,0.f,0.f,0.f};
  #pragma unroll
  for (int kt = 0; kt < 2; ++kt) {
    short8v aF[2];
    #pragma unroll
    for (int rl = 0; rl < 2; ++rl)
      aF[rl] = *(const short8v*)&attrG[(base + rl*16 + r16) * 64 + kt*32 + g4*8];
    #pragma unroll
    for (int ct = 0; ct < 8; ++ct) {
      short8v bF = *(const short8v*)&npWt[(ct*16 + r16) * 64 + kt*32 + g4*8];
      #pragma unroll
      for (int rl = 0; rl < 2; ++rl)
        acc[rl][ct] = __builtin_amdgcn_mfma_f32_16x16x32_bf16(aF[rl], bF, acc[rl][ct], 0, 0, 0);
    }
  }
  short8v hvB[4];
  #pragma unroll
  for (int r = 0; r < 4; ++r) {
    int s = __shfl(srcR, 16 + g4 * 4 + r, 64);
    hvB[r] = *(const short8v*)&xnb[(size_t)s * H + r16 * 8];
  }
  float bb[8];
  #pragma unroll
  for (int ct = 0; ct < 8; ++ct) bb[ct] = npb[ct*16 + r16];
  float vsum[8];
  int pdst = -1;
  #pragma unroll
  for (int rl = 0; rl < 2; ++rl) {
    int d0  = __shfl(dstR, rl*16, 64);
    int d15 = __shfl(dstR, rl*16 + 15, 64);
    if (d0 == d15) {
      float part[8];
      #pragma unroll
      for (int ct = 0; ct < 8; ++ct) part[ct] = 0.f;
      #pragma unroll
      for (int r = 0; r < 4; ++r) {
        int el = g4*4 + r;
        float Ce = __shfl(CR, rl*16 + el, 64);
        int se = __shfl(srcR, rl*16 + el, 64);
        float m = (se != d0) ? Ce : 0.f;
        #pragma unroll
        for (int ct = 0; ct < 8; ++ct) {
          float hval = b2f((u16)(rl ? hvB[r][ct] : hvA[r][ct]));
          part[ct] += (acc[rl][ct][r] + bb[ct]) * m * hval;
        }
      }
      #pragma unroll
      for (int ct = 0; ct < 8; ++ct) {
        part[ct] += __shfl_xor(part[ct], 16, 64);
        part[ct] += __shfl_xor(part[ct], 32, 64);
      }
      if (g4 == 0) {
        if (d0 != pdst) {
          if (pdst >= 0) {
            float* ap = agg + (size_t)pdst * H + r16 * 8;
            #pragma unroll
            for (int ct = 0; ct < 8; ++ct) atomicAdd(ap + ct, vsum[ct]);
          }
          #pragma unroll
          for (int ct = 0; ct < 8; ++ct) vsum[ct] = 0.f;
          pdst = d0;
        }
        #pragma unroll
        for (int ct = 0; ct < 8; ++ct) vsum[ct] += part[ct];
      }
    } else {
      #pragma unroll
      for (int r = 0; r < 4; ++r) {
        int el = g4*4 + r;
        int dn = __shfl(dstR, rl*16 + el, 64);
        float Ce = __shfl(CR, rl*16 + el, 64);
        int se = __shfl(srcR, rl*16 + el, 64);
        float m = (se != dn) ? Ce : 0.f;
        if (dn != pdst) {
          if (pdst >= 0) {
            float* ap = agg + (size_t)pdst * H + r16 * 8;
            #pragma unroll
            for (int ct = 0; ct < 8; ++ct) atomicAdd(ap + ct, vsum[ct]);
          }
          #pragma unroll
          for (int ct = 0; ct < 8; ++ct) vsum[ct] = 0.f;
          pdst = dn;
        }
        #pragma unroll
        for (int ct = 0; ct < 8; ++ct) {
          float hval = b2f((u16)(rl ? hvB[r][ct] : hvA[r][ct]));
          vsum[ct] += (acc[rl][ct][r] + bb[ct]) * m * hval;
        }
      }
    }
  }
  if (pdst >= 0) {
    float* ap = agg + (size_t)pdst * H + r16 * 8;
    #pragma unroll
    for (int ct = 0; ct < 8; ++ct) atomicAdd(ap + ct, vsum[ct]);
  }
}

// ---------------- MFMA CFConv: t1-only LDS, direct permuted gathers ----------------
__global__ __launch_bounds__(256) void k_cf2(
    const int* __restrict__ srcS, const int* __restrict__ dstS,
    const float* __restrict__ CS, const u16* __restrict__ attrG,
    const u16* __restrict__ w1t, const float* __restrict__ b1,
    const u16* __restrict__ w2t, const float* __restrict__ b2,
    const u16* __restrict__ h, float* __restrict__ agg)
{
  __shared__ __align__(16) u16 s_t1[128 * 72];
  int tid = threadIdx.x;
  int lane = tid & 63, wv = tid >> 6;
  int r16 = lane & 15, g4 = lane >> 4;
  long base = (long)blockIdx.x * 128 + wv * 32;
  int wrow = wv * 32;
  int e32 = lane & 31;
  int srcR = srcS[base + e32];
  int dstR = dstS[base + e32];
  float CR = CS[base + e32];
  // band A h gather (permuted h)
  short8v hvA[4];
  #pragma unroll
  for (int r = 0; r < 4; ++r) {
    int s = __shfl(srcR, g4 * 4 + r, 64);
    hvA[r] = *(const short8v*)&h[(size_t)s * H + r16 * 8];
  }
  // GEMM1: attr @ W1t
  f32x4 acc1[2][8];
  #pragma unroll
  for (int rl = 0; rl < 2; ++rl)
    for (int ct = 0; ct < 8; ++ct) acc1[rl][ct] = (f32x4){0.f,0.f,0.f,0.f};
  #pragma unroll
  for (int kt = 0; kt < 2; ++kt) {
    short8v aF[2];
    #pragma unroll
    for (int rl = 0; rl < 2; ++rl)
      aF[rl] = *(const short8v*)&attrG[(base + rl*16 + r16) * 64 + kt*32 + g4*8];
    #pragma unroll
    for (int ct = 0; ct < 8; ++ct) {
      short8v bF = *(const short8v*)&w1t[(ct*16 + r16) * 64 + kt*32 + g4*8];
      #pragma unroll
      for (int rl = 0; rl < 2; ++rl)
        acc1[rl][ct] = __builtin_amdgcn_mfma_f32_16x16x32_bf16(aF[rl], bF, acc1[rl][ct], 0, 0, 0);
    }
  }
  // K-split GEMM2 via wave-local t1
  f32x4 acc2[2][8];
  #pragma unroll
  for (int rl = 0; rl < 2; ++rl)
    for (int ct = 0; ct < 8; ++ct) acc2[rl][ct] = (f32x4){0.f,0.f,0.f,0.f};
  #pragma unroll
  for (int half = 0; half < 2; ++half) {
    #pragma unroll
    for (int ct4 = 0; ct4 < 4; ++ct4) {
      int ct = half*4 + ct4;
      float bbv = b1[ct*16 + r16];
      #pragma unroll
      for (int rl = 0; rl < 2; ++rl) {
        int rbase = wrow + rl*16 + g4*4;
        #pragma unroll
        for (int r = 0; r < 4; ++r) {
          float v = acc1[rl][ct][r] + bbv;
          v = v / (1.f + __expf(-v));
          s_t1[(rbase + r) * 72 + ct4*16 + r16] = f2b(v);
        }
      }
    }
    #pragma unroll
    for (int kt2 = 0; kt2 < 2; ++kt2) {
      short8v aF[2];
      #pragma unroll
      for (int rl = 0; rl < 2; ++rl)
        aF[rl] = *(const short8v*)&s_t1[(wrow + rl*16 + r16) * 72 + kt2*32 + g4*8];
      #pragma unroll
      for (int ct = 0; ct < 8; ++ct) {
        short8v bF = *(const short8v*)&w2t[(ct*16 + r16) * 136 + half*64 + kt2*32 + g4*8];
        #pragma unroll
        for (int rl = 0; rl < 2; ++rl)
          acc2[rl][ct] = __builtin_amdgcn_mfma_f32_16x16x32_bf16(aF[rl], bF, acc2[rl][ct], 0, 0, 0);
      }
    }
  }
  // band B h gather (hides under epilogue A)
  short8v hvB[4];
  #pragma unroll
  for (int r = 0; r < 4; ++r) {
    int s = __shfl(srcR, 16 + g4 * 4 + r, 64);
    hvB[r] = *(const short8v*)&h[(size_t)s * H + r16 * 8];
  }
  float bb2[8];
  #pragma unroll
  for (int ct = 0; ct < 8; ++ct) bb2[ct] = b2[ct*16 + r16];
  float vsum[8];
  int pdst = -1;
  #pragma unroll
  for (int rl = 0; rl < 2; ++rl) {
    int d0  = __shfl(dstR, rl*16, 64);
    int d15 = __shfl(dstR, rl*16 + 15, 64);
    if (d0 == d15) {
      float part[8];
      #pragma unroll
      for (int ct = 0; ct < 8; ++ct) part[ct] = 0.f;
      #pragma unroll
      for (int r = 0; r < 4; ++r) {
        int el = g4*4 + r;
        float Ce = __shfl(CR, rl*16 + el, 64);
        #pragma unroll
        for (int ct = 0; ct < 8; ++ct) {
          float hval = b2f((u16)(rl ? hvB[r][ct] : hvA[r][ct]));
          part[ct] += (acc2[rl][ct][r] + bb2[ct]) * Ce * hval;
        }
      }
      #pragma unroll
      for (int ct = 0; ct < 8; ++ct) {
        part[ct] += __shfl_xor(part[ct], 16, 64);
        part[ct] += __shfl_xor(part[ct], 32, 64);
      }
      if (g4 == 0) {
        if (d0 != pdst) {
          if (pdst >= 0) {
            float* ap = agg + (size_t)pdst * H + r16 * 8;
            #pragma unroll
            for (int ct = 0; ct < 8; ++ct) atomicAdd(ap + ct, vsum[ct]);
          }
          #pragma unroll
          for (int ct = 0; ct < 8; ++ct) vsum[ct] = 0.f;
          pdst = d0;
        }
        #pragma unroll
        for (int ct = 0; ct < 8; ++ct) vsum[ct] += part[ct];
      }
    } else {
      #pragma unroll
      for (int r = 0; r < 4; ++r) {
        int el = g4*4 + r;
        int dn = __shfl(dstR, rl*16 + el, 64);
        float Ce = __shfl(CR, rl*16 + el, 64);
        if (dn != pdst) {
          if (pdst >= 0) {
            float* ap = agg + (size_t)pdst * H + r16 * 8;
            #pragma unroll
            for (int ct = 0; ct < 8; ++ct) atomicAdd(ap + ct, vsum[ct]);
          }
          #pragma unroll
          for (int ct = 0; ct < 8; ++ct) vsum[ct] = 0.f;
          pdst = dn;
        }
        #pragma unroll
        for (int ct = 0; ct < 8; ++ct) {
          float hval = b2f((u16)(rl ? hvB[r][ct] : hvA[r][ct]));
          vsum[ct] += (acc2[rl][ct][r] + bb2[ct]) * Ce * hval;
        }
      }
    }
  }
  if (pdst >= 0) {
    float* ap = agg + (size_t)pdst * H + r16 * 8;
    #pragma unroll
    for (int ct = 0; ct < 8; ++ct) atomicAdd(ap + ct, vsum[ct]);
  }
}

// ---------------- launcher ----------------
extern "C" void kernel_launch(void* const* d_in, const int* in_sizes, int n_in,
                              void* d_out, int out_size, void* d_ws, size_t ws_size,
                              hipStream_t stream) {
  int bo = (n_in >= 4 && in_sizes[3] == NN) ? 0 : -1;  // batch present?
  const int*   z     = (const int*)d_in[0];
  const float* pos   = (const float*)d_in[1];
  const int*   ei    = (const int*)d_in[2];
  const float* emb   = (const float*)d_in[4 + bo];
  const float* nemb  = (const float*)d_in[5 + bo];
  const float* npW   = (const float*)d_in[6 + bo];
  const float* npb   = (const float*)d_in[7 + bo];
  const float* cW    = (const float*)d_in[8 + bo];
  const float* cb    = (const float*)d_in[9 + bo];
  const float* means = (const float*)d_in[10 + bo];
  const float* betas = (const float*)d_in[11 + bo];
  const float* W1    = (const float*)d_in[12 + bo];
  const float* b1    = (const float*)d_in[13 + bo];
  const float* W2    = (const float*)d_in[14 + bo];
  const float* b2    = (const float*)d_in[15 + bo];
  const float* l1W   = (const float*)d_in[16 + bo];
  const float* l2W   = (const float*)d_in[17 + bo];
  const float* l2b   = (const float*)d_in[18 + bo];
  const float* lW    = (const float*)d_in[19 + bo];
  const float* lb    = (const float*)d_in[20 + bo];

  char* w = (char*)d_ws;
  auto alloc = [&](size_t bytes) { char* p = w; w += (bytes + 255) & ~(size_t)255; return p; };
  int*   counts = (int*)  alloc((size_t)NN * 4);
  int*   cursor = (int*)  alloc((size_t)NN * 4);
  int*   perm   = (int*)  alloc((size_t)NE * 4);
  int*   srcS   = (int*)  alloc((size_t)NE * 4);
  int*   dstS   = (int*)  alloc((size_t)NE * 4);
  float* CS     = (float*)alloc((size_t)NE * 4);
  u16*   attrG  = (u16*)  alloc((size_t)NE * 64 * 2);
  u16*   npWt   = (u16*)  alloc((size_t)128 * 64 * 2);
  u16*   w1tA   = (u16*)  alloc((size_t)NL * 128 * 64 * 2);
  u16*   w2tA   = (u16*)  alloc((size_t)NL * 128 * 136 * 2);
  float* xbuf   = (float*)alloc((size_t)NN * H * 4);
  float* agg    = (float*)alloc((size_t)NN * H * 4);
  u16*   xnb    = (u16*)  alloc((size_t)NN * H * 2);
  u16*   hbuf   = (u16*)  alloc((size_t)NN * H * 2);

  dim3 b256(256);
  int gE256 = (NE + 255) / 256;        // 2500
  int gNH   = (NN * H + 255) / 256;    // 10000
  int gCF   = NE / 128;                // 5000
  int gG    = NN / 32;                 // 625

  k_zero_i32<<<(NN + 255) / 256, b256, 0, stream>>>(counts, NN);
  k_hist<<<gE256, b256, 0, stream>>>(ei, counts);
  k_scan<<<1, 1024, 0, stream>>>(counts, cursor);
  k_place<<<gE256, b256, 0, stream>>>(ei, cursor, perm);
  k_edge<<<gE256, b256, 0, stream>>>(ei, perm, pos, means, betas, srcS, dstS, CS, attrG);
  k_prepw<<<(161792 + 255) / 256, b256, 0, stream>>>(npW, W1, W2, npWt, w1tA, w2tA);
  k_embed<<<gNH, b256, 0, stream>>>(z, emb, nemb, xbuf, xnb, agg);

  k_nbr2<<<gCF, b256, 0, stream>>>(srcS, dstS, CS, attrG, npWt, npb, xnb, agg);
  k_combine<<<gG, b256, 0, stream>>>(xbuf, agg, cW, cb, l1W, xbuf, hbuf);

  for (int l = 0; l < NL; ++l) {
    k_cf2<<<gCF, b256, 0, stream>>>(srcS, dstS, CS, attrG,
                                    w1tA + (size_t)l * 128 * 64, b1 + (size_t)l * H,
                                    w2tA + (size_t)l * 128 * 136, b2 + (size_t)l * H,
                                    hbuf, agg);
    const float* l1Wn = (l + 1 < NL) ? (l1W + (size_t)(l + 1) * H * H) : nullptr;
    float* xo = (l == NL - 1) ? (float*)d_out : xbuf;
    k_gemmF2<<<gG, b256, 0, stream>>>(agg, l2W + (size_t)l * H * H, l2b + (size_t)l * H,
                                      lW + (size_t)l * H * H, lb + (size_t)l * H,
                                      xbuf, xo, l1Wn, hbuf);
  }
}

// Round 12
// 1592.846 us; speedup vs baseline: 2.2120x; 2.2120x over previous
//
#include <hip/hip_runtime.h>
#include <hip/hip_bf16.h>
#include <math.h>

#define NN 20000
#define NE 640000
#define H  128
#define RB 50
#define NL 6

typedef unsigned short u16;
typedef __attribute__((ext_vector_type(8))) short short8v;
typedef __attribute__((ext_vector_type(4))) float f32x4;

// gather permutation (h/xn only): col c -> slot (c&15)*8 + (c>>4)
__device__ __forceinline__ u16 f2b(float v) {
  unsigned x = __float_as_uint(v);
  unsigned r = (x + 0x7FFFu + ((x >> 16) & 1u)) >> 16;
  return (u16)r;
}
__device__ __forceinline__ float b2f(u16 u) {
  return __uint_as_float(((unsigned int)u) << 16);
}

// ---------------- sort machinery ----------------
__global__ void k_zero_i32(int* __restrict__ p, int n) {
  int i = blockIdx.x * blockDim.x + threadIdx.x;
  if (i < n) p[i] = 0;
}
__global__ void k_hist(const int* __restrict__ ei, int* __restrict__ counts) {
  int e = blockIdx.x * blockDim.x + threadIdx.x;
  if (e < NE) atomicAdd(&counts[ei[NE + e]], 1);
}
__global__ void k_scan(const int* __restrict__ counts, int* __restrict__ cursor) {
  __shared__ int buf[1024];
  __shared__ int carry;
  int tid = threadIdx.x;
  if (tid == 0) carry = 0;
  __syncthreads();
  for (int base = 0; base < NN; base += 1024) {
    int i = base + tid;
    int v = (i < NN) ? counts[i] : 0;
    buf[tid] = v;
    __syncthreads();
    for (int off = 1; off < 1024; off <<= 1) {
      int t = (tid >= off) ? buf[tid - off] : 0;
      __syncthreads();
      buf[tid] += t;
      __syncthreads();
    }
    int incl = buf[tid];
    int excl = incl - v + carry;
    if (i < NN) cursor[i] = excl;
    __syncthreads();
    if (tid == 1023) carry += incl;
    __syncthreads();
  }
}
__global__ void k_place(const int* __restrict__ ei, int* __restrict__ cursor,
                        int* __restrict__ perm) {
  int e = blockIdx.x * blockDim.x + threadIdx.x;
  if (e < NE) {
    int d = ei[NE + e];
    int p = atomicAdd(&cursor[d], 1);
    perm[p] = e;
  }
}

// ---------------- edge precompute ----------------
__global__ void k_edge(const int* __restrict__ ei, const int* __restrict__ perm,
                       const float* __restrict__ pos, const float* __restrict__ means,
                       const float* __restrict__ betas,
                       int* __restrict__ srcS, int* __restrict__ dstS,
                       float* __restrict__ CS, u16* __restrict__ attrG) {
  int p = blockIdx.x * 256 + threadIdx.x;
  if (p >= NE) return;
  int e = perm[p];
  int s = ei[e], t = ei[NE + e];
  srcS[p] = s; dstS[p] = t;
  float dx = pos[3*s]   - pos[3*t];
  float dy = pos[3*s+1] - pos[3*t+1];
  float dz = pos[3*s+2] - pos[3*t+2];
  float d = sqrtf(dx*dx + dy*dy + dz*dz);
  float C = 0.5f * (cosf(d * 0.628318530717958647692f) + 1.0f);
  if (d >= 5.0f) C = 0.f;
  CS[p] = C;
  float tv = expf(-d);
  u16* row = attrG + (size_t)p * 64;
  for (int k = 0; k < RB; ++k) {
    float diff = tv - means[k];
    row[k] = f2b(C * expf(-betas[k] * diff * diff));
  }
  for (int k = RB; k < 64; ++k) row[k] = 0;
}

// ---------------- weight pre-transpose/convert to bf16 ----------------
__global__ void k_prepw(const float* __restrict__ npW, const float* __restrict__ W1,
                        const float* __restrict__ W2, u16* __restrict__ npWt,
                        u16* __restrict__ w1tA, u16* __restrict__ w2tA) {
  int i = blockIdx.x * 256 + threadIdx.x;
  if (i < 8192) {
    int n = i >> 6, k = i & 63;
    npWt[i] = (k < RB) ? f2b(npW[k * H + n]) : (u16)0;
  } else if (i < 57344) {
    int j = i - 8192;
    int l = j >> 13, r = j & 8191;
    int n = r >> 6, k = r & 63;
    w1tA[j] = (k < RB) ? f2b(W1[(size_t)l * RB * H + (size_t)k * H + n]) : (u16)0;
  } else if (i < 161792) {
    int j = i - 57344;
    int l = j / 17408, r = j % 17408;
    int n = r / 136, k = r % 136;
    w2tA[j] = (k < H) ? f2b(W2[(size_t)l * H * H + (size_t)k * H + n]) : (u16)0;
  }
}

// x f32 natural; xn bf16 PERMUTED; agg (natural) zero-init
__global__ void k_embed(const int* __restrict__ z, const float* __restrict__ emb,
                        const float* __restrict__ nemb,
                        float* __restrict__ x, u16* __restrict__ xnb,
                        float* __restrict__ aggz) {
  int i = blockIdx.x * blockDim.x + threadIdx.x;
  if (i >= NN * H) return;
  int n = i >> 7, c = i & (H - 1);
  long o = (long)z[n] * H + c;
  x[i] = emb[o];
  xnb[(size_t)n * H + ((c & 15) * 8 + (c >> 4))] = f2b(nemb[o]);
  aggz[i] = 0.f;
}

// ---------------- combine: x = [x||agg]@cW + cb;  h0 = x@l1W0 (bf16 permuted) ----------------
__global__ __launch_bounds__(256) void k_combine(
    const float* __restrict__ xb, float* __restrict__ ag,
    const float* __restrict__ cW, const float* __restrict__ cb,
    const float* __restrict__ l1W0, float* __restrict__ xout,
    u16* __restrict__ hb)
{
  __shared__ float sX[32][132];
  __shared__ float sG[32][132];
  int tid = threadIdx.x;
  int n0 = blockIdx.x * 32;
  #pragma unroll
  for (int j = 0; j < 4; ++j) {
    int f4 = tid + j * 256;
    int r = f4 >> 5, c4 = f4 & 31;
    *(float4*)&sX[r][c4 * 4] = *(const float4*)&xb[(size_t)(n0 + r) * H + c4 * 4];
    *(float4*)&sG[r][c4 * 4] = *(const float4*)&ag[(size_t)(n0 + r) * H + c4 * 4];
    *(float4*)&ag[(size_t)(n0 + r) * H + c4 * 4] = make_float4(0.f, 0.f, 0.f, 0.f);
  }
  __syncthreads();
  int g = tid >> 5;
  int c0 = (tid & 31) * 4;
  int eb = g * 4;
  float acc[4][4];
  #pragma unroll
  for (int i = 0; i < 4; ++i)
    for (int j = 0; j < 4; ++j) acc[i][j] = 0.f;
  for (int k = 0; k < H; ++k) {
    float4 wv = *(const float4*)&cW[(size_t)k * H + c0];
    #pragma unroll
    for (int i = 0; i < 4; ++i) {
      float a = sX[eb + i][k];
      acc[i][0] += a * wv.x; acc[i][1] += a * wv.y;
      acc[i][2] += a * wv.z; acc[i][3] += a * wv.w;
    }
  }
  for (int k = 0; k < H; ++k) {
    float4 wv = *(const float4*)&cW[(size_t)(H + k) * H + c0];
    #pragma unroll
    for (int i = 0; i < 4; ++i) {
      float a = sG[eb + i][k];
      acc[i][0] += a * wv.x; acc[i][1] += a * wv.y;
      acc[i][2] += a * wv.z; acc[i][3] += a * wv.w;
    }
  }
  float4 bv = *(const float4*)&cb[c0];
  __syncthreads();
  #pragma unroll
  for (int i = 0; i < 4; ++i) {
    int n = n0 + eb + i;
    float o0 = acc[i][0] + bv.x, o1 = acc[i][1] + bv.y;
    float o2 = acc[i][2] + bv.z, o3 = acc[i][3] + bv.w;
    *(float4*)&xout[(size_t)n * H + c0] = make_float4(o0, o1, o2, o3);
    sX[eb + i][c0] = o0; sX[eb + i][c0+1] = o1;
    sX[eb + i][c0+2] = o2; sX[eb + i][c0+3] = o3;
  }
  __syncthreads();
  #pragma unroll
  for (int i = 0; i < 4; ++i)
    for (int j = 0; j < 4; ++j) acc[i][j] = 0.f;
  for (int k = 0; k < H; ++k) {
    float4 wv = *(const float4*)&l1W0[(size_t)k * H + c0];
    #pragma unroll
    for (int i = 0; i < 4; ++i) {
      float a = sX[eb + i][k];
      acc[i][0] += a * wv.x; acc[i][1] += a * wv.y;
      acc[i][2] += a * wv.z; acc[i][3] += a * wv.w;
    }
  }
  int pbase = (c0 & 15) * 8 + (c0 >> 4);
  #pragma unroll
  for (int i = 0; i < 4; ++i) {
    int n = n0 + eb + i;
    #pragma unroll
    for (int j = 0; j < 4; ++j)
      hb[(size_t)n * H + pbase + 8 * j] = f2b(acc[i][j]);
  }
}

// ---------------- fused lin2+lin (+next-layer lin1) ----------------
__global__ __launch_bounds__(256) void k_gemmF2(
    float* __restrict__ A, const float* __restrict__ W2,
    const float* __restrict__ b2, const float* __restrict__ W3,
    const float* __restrict__ b3, const float* __restrict__ xin,
    float* __restrict__ xout, const float* __restrict__ l1Wn,
    u16* __restrict__ hb)
{
  __shared__ float sA[32][132];
  __shared__ float sT[32][132];
  int tid = threadIdx.x;
  int n0 = blockIdx.x * 32;
  #pragma unroll
  for (int j = 0; j < 4; ++j) {
    int f4 = tid + j * 256;
    int r = f4 >> 5, c4 = f4 & 31;
    *(float4*)&sA[r][c4 * 4] = *(const float4*)&A[(size_t)(n0 + r) * H + c4 * 4];
    *(float4*)&A[(size_t)(n0 + r) * H + c4 * 4] = make_float4(0.f, 0.f, 0.f, 0.f);
  }
  __syncthreads();
  int g = tid >> 5;
  int c0 = (tid & 31) * 4;
  int eb = g * 4;
  float acc[4][4];
  #pragma unroll
  for (int i = 0; i < 4; ++i)
    for (int j = 0; j < 4; ++j) acc[i][j] = 0.f;
  for (int k = 0; k < H; ++k) {
    float4 wv = *(const float4*)&W2[(size_t)k * H + c0];
    #pragma unroll
    for (int i = 0; i < 4; ++i) {
      float a = sA[eb + i][k];
      acc[i][0] += a * wv.x; acc[i][1] += a * wv.y;
      acc[i][2] += a * wv.z; acc[i][3] += a * wv.w;
    }
  }
  float4 bv2 = *(const float4*)&b2[c0];
  #pragma unroll
  for (int i = 0; i < 4; ++i) {
    float t0 = acc[i][0] + bv2.x, t1 = acc[i][1] + bv2.y;
    float t2 = acc[i][2] + bv2.z, t3 = acc[i][3] + bv2.w;
    sT[eb + i][c0 + 0] = t0 / (1.f + __expf(-t0));
    sT[eb + i][c0 + 1] = t1 / (1.f + __expf(-t1));
    sT[eb + i][c0 + 2] = t2 / (1.f + __expf(-t2));
    sT[eb + i][c0 + 3] = t3 / (1.f + __expf(-t3));
  }
  __syncthreads();
  #pragma unroll
  for (int i = 0; i < 4; ++i)
    for (int j = 0; j < 4; ++j) acc[i][j] = 0.f;
  for (int k = 0; k < H; ++k) {
    float4 wv = *(const float4*)&W3[(size_t)k * H + c0];
    #pragma unroll
    for (int i = 0; i < 4; ++i) {
      float a = sT[eb + i][k];
      acc[i][0] += a * wv.x; acc[i][1] += a * wv.y;
      acc[i][2] += a * wv.z; acc[i][3] += a * wv.w;
    }
  }
  float4 bv3 = *(const float4*)&b3[c0];
  #pragma unroll
  for (int i = 0; i < 4; ++i) {
    int n = n0 + eb + i;
    float4 xv = *(const float4*)&xin[(size_t)n * H + c0];
    float o0 = xv.x + acc[i][0] + bv3.x, o1 = xv.y + acc[i][1] + bv3.y;
    float o2 = xv.z + acc[i][2] + bv3.z, o3 = xv.w + acc[i][3] + bv3.w;
    *(float4*)&xout[(size_t)n * H + c0] = make_float4(o0, o1, o2, o3);
    sA[eb + i][c0] = o0; sA[eb + i][c0+1] = o1;
    sA[eb + i][c0+2] = o2; sA[eb + i][c0+3] = o3;
  }
  if (l1Wn) {
    __syncthreads();
    #pragma unroll
    for (int i = 0; i < 4; ++i)
      for (int j = 0; j < 4; ++j) acc[i][j] = 0.f;
    for (int k = 0; k < H; ++k) {
      float4 wv = *(const float4*)&l1Wn[(size_t)k * H + c0];
      #pragma unroll
      for (int i = 0; i < 4; ++i) {
        float a = sA[eb + i][k];
        acc[i][0] += a * wv.x; acc[i][1] += a * wv.y;
        acc[i][2] += a * wv.z; acc[i][3] += a * wv.w;
      }
    }
    int pbase = (c0 & 15) * 8 + (c0 >> 4);
    #pragma unroll
    for (int i = 0; i < 4; ++i) {
      int n = n0 + eb + i;
      #pragma unroll
      for (int j = 0; j < 4; ++j)
        hb[(size_t)n * H + pbase + 8 * j] = f2b(acc[i][j]);
    }
  }
}

// ---------------- LDS-free MFMA neighbor embedding ----------------
__global__ __launch_bounds__(256) void k_nbr2(
    const int* __restrict__ srcS, const int* __restrict__ dstS,
    const float* __restrict__ CS, const u16* __restrict__ attrG,
    const u16* __restrict__ npWt, const float* __restrict__ npb,
    const u16* __restrict__ xnb, float* __restrict__ agg)
{
  int tid = threadIdx.x;
  int lane = tid & 63, wv = tid >> 6;
  int r16 = lane & 15, g4 = lane >> 4;
  long base = (long)blockIdx.x * 128 + wv * 32;
  int e32 = lane & 31;
  int srcR = srcS[base + e32];
  int dstR = dstS[base + e32];
  float CR = CS[base + e32];
  short8v hvA[4];
  #pragma unroll
  for (int r = 0; r < 4; ++r) {
    int s = __shfl(srcR, g4 * 4 + r, 64);
    hvA[r] = *(const short8v*)&xnb[(size_t)s * H + r16 * 8];
  }
  f32x4 acc[2][8];
  #pragma unroll
  for (int rl = 0; rl < 2; ++rl)
    for (int ct = 0; ct < 8; ++ct) acc[rl][ct] = (f32x4){0.f,0.f,0.f,0.f};
  #pragma unroll
  for (int kt = 0; kt < 2; ++kt) {
    short8v aF[2];
    #pragma unroll
    for (int rl = 0; rl < 2; ++rl)
      aF[rl] = *(const short8v*)&attrG[(base + rl*16 + r16) * 64 + kt*32 + g4*8];
    #pragma unroll
    for (int ct = 0; ct < 8; ++ct) {
      short8v bF = *(const short8v*)&npWt[(ct*16 + r16) * 64 + kt*32 + g4*8];
      #pragma unroll
      for (int rl = 0; rl < 2; ++rl)
        acc[rl][ct] = __builtin_amdgcn_mfma_f32_16x16x32_bf16(aF[rl], bF, acc[rl][ct], 0, 0, 0);
    }
  }
  short8v hvB[4];
  #pragma unroll
  for (int r = 0; r < 4; ++r) {
    int s = __shfl(srcR, 16 + g4 * 4 + r, 64);
    hvB[r] = *(const short8v*)&xnb[(size_t)s * H + r16 * 8];
  }
  float bb[8];
  #pragma unroll
  for (int ct = 0; ct < 8; ++ct) bb[ct] = npb[ct*16 + r16];
  float vsum[8];
  int pdst = -1;
  #pragma unroll
  for (int rl = 0; rl < 2; ++rl) {
    int d0  = __shfl(dstR, rl*16, 64);
    int d15 = __shfl(dstR, rl*16 + 15, 64);
    if (d0 == d15) {
      float part[8];
      #pragma unroll
      for (int ct = 0; ct < 8; ++ct) part[ct] = 0.f;
      #pragma unroll
      for (int r = 0; r < 4; ++r) {
        int el = g4*4 + r;
        float Ce = __shfl(CR, rl*16 + el, 64);
        int se = __shfl(srcR, rl*16 + el, 64);
        float m = (se != d0) ? Ce : 0.f;
        #pragma unroll
        for (int ct = 0; ct < 8; ++ct) {
          float hval = b2f((u16)(rl ? hvB[r][ct] : hvA[r][ct]));
          part[ct] += (acc[rl][ct][r] + bb[ct]) * m * hval;
        }
      }
      #pragma unroll
      for (int ct = 0; ct < 8; ++ct) {
        part[ct] += __shfl_xor(part[ct], 16, 64);
        part[ct] += __shfl_xor(part[ct], 32, 64);
      }
      if (g4 == 0) {
        if (d0 != pdst) {
          if (pdst >= 0) {
            float* ap = agg + (size_t)pdst * H + r16;
            #pragma unroll
            for (int ct = 0; ct < 8; ++ct) atomicAdd(ap + ct*16, vsum[ct]);
          }
          #pragma unroll
          for (int ct = 0; ct < 8; ++ct) vsum[ct] = 0.f;
          pdst = d0;
        }
        #pragma unroll
        for (int ct = 0; ct < 8; ++ct) vsum[ct] += part[ct];
      }
    } else {
      #pragma unroll
      for (int r = 0; r < 4; ++r) {
        int el = g4*4 + r;
        int dn = __shfl(dstR, rl*16 + el, 64);
        float Ce = __shfl(CR, rl*16 + el, 64);
        int se = __shfl(srcR, rl*16 + el, 64);
        float m = (se != dn) ? Ce : 0.f;
        if (dn != pdst) {
          if (pdst >= 0) {
            float* ap = agg + (size_t)pdst * H + r16;
            #pragma unroll
            for (int ct = 0; ct < 8; ++ct) atomicAdd(ap + ct*16, vsum[ct]);
          }
          #pragma unroll
          for (int ct = 0; ct < 8; ++ct) vsum[ct] = 0.f;
          pdst = dn;
        }
        #pragma unroll
        for (int ct = 0; ct < 8; ++ct) {
          float hval = b2f((u16)(rl ? hvB[r][ct] : hvA[r][ct]));
          vsum[ct] += (acc[rl][ct][r] + bb[ct]) * m * hval;
        }
      }
    }
  }
  if (pdst >= 0) {
    float* ap = agg + (size_t)pdst * H + r16;
    #pragma unroll
    for (int ct = 0; ct < 8; ++ct) atomicAdd(ap + ct*16, vsum[ct]);
  }
}

// ---------------- MFMA CFConv: t1-only LDS, permuted reg gathers, natural atomics ----------------
__global__ __launch_bounds__(256) void k_cf2(
    const int* __restrict__ srcS, const int* __restrict__ dstS,
    const float* __restrict__ CS, const u16* __restrict__ attrG,
    const u16* __restrict__ w1t, const float* __restrict__ b1,
    const u16* __restrict__ w2t, const float* __restrict__ b2,
    const u16* __restrict__ h, float* __restrict__ agg)
{
  __shared__ __align__(16) u16 s_t1[128 * 72];
  int tid = threadIdx.x;
  int lane = tid & 63, wv = tid >> 6;
  int r16 = lane & 15, g4 = lane >> 4;
  long base = (long)blockIdx.x * 128 + wv * 32;
  int wrow = wv * 32;
  int e32 = lane & 31;
  int srcR = srcS[base + e32];
  int dstR = dstS[base + e32];
  float CR = CS[base + e32];
  short8v hvA[4];
  #pragma unroll
  for (int r = 0; r < 4; ++r) {
    int s = __shfl(srcR, g4 * 4 + r, 64);
    hvA[r] = *(const short8v*)&h[(size_t)s * H + r16 * 8];
  }
  // GEMM1: attr @ W1t
  f32x4 acc1[2][8];
  #pragma unroll
  for (int rl = 0; rl < 2; ++rl)
    for (int ct = 0; ct < 8; ++ct) acc1[rl][ct] = (f32x4){0.f,0.f,0.f,0.f};
  #pragma unroll
  for (int kt = 0; kt < 2; ++kt) {
    short8v aF[2];
    #pragma unroll
    for (int rl = 0; rl < 2; ++rl)
      aF[rl] = *(const short8v*)&attrG[(base + rl*16 + r16) * 64 + kt*32 + g4*8];
    #pragma unroll
    for (int ct = 0; ct < 8; ++ct) {
      short8v bF = *(const short8v*)&w1t[(ct*16 + r16) * 64 + kt*32 + g4*8];
      #pragma unroll
      for (int rl = 0; rl < 2; ++rl)
        acc1[rl][ct] = __builtin_amdgcn_mfma_f32_16x16x32_bf16(aF[rl], bF, acc1[rl][ct], 0, 0, 0);
    }
  }
  // K-split GEMM2 via wave-local t1
  f32x4 acc2[2][8];
  #pragma unroll
  for (int rl = 0; rl < 2; ++rl)
    for (int ct = 0; ct < 8; ++ct) acc2[rl][ct] = (f32x4){0.f,0.f,0.f,0.f};
  #pragma unroll
  for (int half = 0; half < 2; ++half) {
    #pragma unroll
    for (int ct4 = 0; ct4 < 4; ++ct4) {
      int ct = half*4 + ct4;
      float bbv = b1[ct*16 + r16];
      #pragma unroll
      for (int rl = 0; rl < 2; ++rl) {
        int rbase = wrow + rl*16 + g4*4;
        #pragma unroll
        for (int r = 0; r < 4; ++r) {
          float v = acc1[rl][ct][r] + bbv;
          v = v / (1.f + __expf(-v));
          s_t1[(rbase + r) * 72 + ct4*16 + r16] = f2b(v);
        }
      }
    }
    #pragma unroll
    for (int kt2 = 0; kt2 < 2; ++kt2) {
      short8v aF[2];
      #pragma unroll
      for (int rl = 0; rl < 2; ++rl)
        aF[rl] = *(const short8v*)&s_t1[(wrow + rl*16 + r16) * 72 + kt2*32 + g4*8];
      #pragma unroll
      for (int ct = 0; ct < 8; ++ct) {
        short8v bF = *(const short8v*)&w2t[(ct*16 + r16) * 136 + half*64 + kt2*32 + g4*8];
        #pragma unroll
        for (int rl = 0; rl < 2; ++rl)
          acc2[rl][ct] = __builtin_amdgcn_mfma_f32_16x16x32_bf16(aF[rl], bF, acc2[rl][ct], 0, 0, 0);
      }
    }
  }
  // band B h gather (hides under epilogue A)
  short8v hvB[4];
  #pragma unroll
  for (int r = 0; r < 4; ++r) {
    int s = __shfl(srcR, 16 + g4 * 4 + r, 64);
    hvB[r] = *(const short8v*)&h[(size_t)s * H + r16 * 8];
  }
  float bb2[8];
  #pragma unroll
  for (int ct = 0; ct < 8; ++ct) bb2[ct] = b2[ct*16 + r16];
  float vsum[8];
  int pdst = -1;
  #pragma unroll
  for (int rl = 0; rl < 2; ++rl) {
    int d0  = __shfl(dstR, rl*16, 64);
    int d15 = __shfl(dstR, rl*16 + 15, 64);
    if (d0 == d15) {
      float part[8];
      #pragma unroll
      for (int ct = 0; ct < 8; ++ct) part[ct] = 0.f;
      #pragma unroll
      for (int r = 0; r < 4; ++r) {
        int el = g4*4 + r;
        float Ce = __shfl(CR, rl*16 + el, 64);
        #pragma unroll
        for (int ct = 0; ct < 8; ++ct) {
          float hval = b2f((u16)(rl ? hvB[r][ct] : hvA[r][ct]));
          part[ct] += (acc2[rl][ct][r] + bb2[ct]) * Ce * hval;
        }
      }
      #pragma unroll
      for (int ct = 0; ct < 8; ++ct) {
        part[ct] += __shfl_xor(part[ct], 16, 64);
        part[ct] += __shfl_xor(part[ct], 32, 64);
      }
      if (g4 == 0) {
        if (d0 != pdst) {
          if (pdst >= 0) {
            float* ap = agg + (size_t)pdst * H + r16;
            #pragma unroll
            for (int ct = 0; ct < 8; ++ct) atomicAdd(ap + ct*16, vsum[ct]);
          }
          #pragma unroll
          for (int ct = 0; ct < 8; ++ct) vsum[ct] = 0.f;
          pdst = d0;
        }
        #pragma unroll
        for (int ct = 0; ct < 8; ++ct) vsum[ct] += part[ct];
      }
    } else {
      #pragma unroll
      for (int r = 0; r < 4; ++r) {
        int el = g4*4 + r;
        int dn = __shfl(dstR, rl*16 + el, 64);
        float Ce = __shfl(CR, rl*16 + el, 64);
        if (dn != pdst) {
          if (pdst >= 0) {
            float* ap = agg + (size_t)pdst * H + r16;
            #pragma unroll
            for (int ct = 0; ct < 8; ++ct) atomicAdd(ap + ct*16, vsum[ct]);
          }
          #pragma unroll
          for (int ct = 0; ct < 8; ++ct) vsum[ct] = 0.f;
          pdst = dn;
        }
        #pragma unroll
        for (int ct = 0; ct < 8; ++ct) {
          float hval = b2f((u16)(rl ? hvB[r][ct] : hvA[r][ct]));
          vsum[ct] += (acc2[rl][ct][r] + bb2[ct]) * Ce * hval;
        }
      }
    }
  }
  if (pdst >= 0) {
    float* ap = agg + (size_t)pdst * H + r16;
    #pragma unroll
    for (int ct = 0; ct < 8; ++ct) atomicAdd(ap + ct*16, vsum[ct]);
  }
}

// ---------------- launcher ----------------
extern "C" void kernel_launch(void* const* d_in, const int* in_sizes, int n_in,
                              void* d_out, int out_size, void* d_ws, size_t ws_size,
                              hipStream_t stream) {
  int bo = (n_in >= 4 && in_sizes[3] == NN) ? 0 : -1;  // batch present?
  const int*   z     = (const int*)d_in[0];
  const float* pos   = (const float*)d_in[1];
  const int*   ei    = (const int*)d_in[2];
  const float* emb   = (const float*)d_in[4 + bo];
  const float* nemb  = (const float*)d_in[5 + bo];
  const float* npW   = (const float*)d_in[6 + bo];
  const float* npb   = (const float*)d_in[7 + bo];
  const float* cW    = (const float*)d_in[8 + bo];
  const float* cb    = (const float*)d_in[9 + bo];
  const float* means = (const float*)d_in[10 + bo];
  const float* betas = (const float*)d_in[11 + bo];
  const float* W1    = (const float*)d_in[12 + bo];
  const float* b1    = (const float*)d_in[13 + bo];
  const float* W2    = (const float*)d_in[14 + bo];
  const float* b2    = (const float*)d_in[15 + bo];
  const float* l1W   = (const float*)d_in[16 + bo];
  const float* l2W   = (const float*)d_in[17 + bo];
  const float* l2b   = (const float*)d_in[18 + bo];
  const float* lW    = (const float*)d_in[19 + bo];
  const float* lb    = (const float*)d_in[20 + bo];

  char* w = (char*)d_ws;
  auto alloc = [&](size_t bytes) { char* p = w; w += (bytes + 255) & ~(size_t)255; return p; };
  int*   counts = (int*)  alloc((size_t)NN * 4);
  int*   cursor = (int*)  alloc((size_t)NN * 4);
  int*   perm   = (int*)  alloc((size_t)NE * 4);
  int*   srcS   = (int*)  alloc((size_t)NE * 4);
  int*   dstS   = (int*)  alloc((size_t)NE * 4);
  float* CS     = (float*)alloc((size_t)NE * 4);
  u16*   attrG  = (u16*)  alloc((size_t)NE * 64 * 2);
  u16*   npWt   = (u16*)  alloc((size_t)128 * 64 * 2);
  u16*   w1tA   = (u16*)  alloc((size_t)NL * 128 * 64 * 2);
  u16*   w2tA   = (u16*)  alloc((size_t)NL * 128 * 136 * 2);
  float* xbuf   = (float*)alloc((size_t)NN * H * 4);
  float* agg    = (float*)alloc((size_t)NN * H * 4);
  u16*   xnb    = (u16*)  alloc((size_t)NN * H * 2);
  u16*   hbuf   = (u16*)  alloc((size_t)NN * H * 2);

  dim3 b256(256);
  int gE256 = (NE + 255) / 256;        // 2500
  int gNH   = (NN * H + 255) / 256;    // 10000
  int gCF   = NE / 128;                // 5000
  int gG    = NN / 32;                 // 625

  k_zero_i32<<<(NN + 255) / 256, b256, 0, stream>>>(counts, NN);
  k_hist<<<gE256, b256, 0, stream>>>(ei, counts);
  k_scan<<<1, 1024, 0, stream>>>(counts, cursor);
  k_place<<<gE256, b256, 0, stream>>>(ei, cursor, perm);
  k_edge<<<gE256, b256, 0, stream>>>(ei, perm, pos, means, betas, srcS, dstS, CS, attrG);
  k_prepw<<<(161792 + 255) / 256, b256, 0, stream>>>(npW, W1, W2, npWt, w1tA, w2tA);
  k_embed<<<gNH, b256, 0, stream>>>(z, emb, nemb, xbuf, xnb, agg);

  k_nbr2<<<gCF, b256, 0, stream>>>(srcS, dstS, CS, attrG, npWt, npb, xnb, agg);
  k_combine<<<gG, b256, 0, stream>>>(xbuf, agg, cW, cb, l1W, xbuf, hbuf);

  for (int l = 0; l < NL; ++l) {
    k_cf2<<<gCF, b256, 0, stream>>>(srcS, dstS, CS, attrG,
                                    w1tA + (size_t)l * 128 * 64, b1 + (size_t)l * H,
                                    w2tA + (size_t)l * 128 * 136, b2 + (size_t)l * H,
                                    hbuf, agg);
    const float* l1Wn = (l + 1 < NL) ? (l1W + (size_t)(l + 1) * H * H) : nullptr;
    float* xo = (l == NL - 1) ? (float*)d_out : xbuf;
    k_gemmF2<<<gG, b256, 0, stream>>>(agg, l2W + (size_t)l * H * H, l2b + (size_t)l * H,
                                      lW + (size_t)l * H * H, lb + (size_t)l * H,
                                      xbuf, xo, l1Wn, hbuf);
  }
}

// Round 13
// 825.817 us; speedup vs baseline: 4.2666x; 1.9288x over previous
//
#include <hip/hip_runtime.h>
#include <hip/hip_bf16.h>
#include <math.h>

#define NN 20000
#define NE 640000
#define H  128
#define RB 50
#define NL 6
#define TBINS 4096

typedef unsigned short u16;
typedef __attribute__((ext_vector_type(8))) short short8v;

// gather permutation (h/xn/tables): col c -> slot (c&15)*8 + (c>>4)
__device__ __forceinline__ u16 f2b(float v) {
  unsigned x = __float_as_uint(v);
  unsigned r = (x + 0x7FFFu + ((x >> 16) & 1u)) >> 16;
  return (u16)r;
}
__device__ __forceinline__ float b2f(u16 u) {
  return __uint_as_float(((unsigned int)u) << 16);
}

// ---------------- sort machinery ----------------
__global__ void k_zero_i32(int* __restrict__ p, int n) {
  int i = blockIdx.x * blockDim.x + threadIdx.x;
  if (i < n) p[i] = 0;
}
__global__ void k_hist(const int* __restrict__ ei, int* __restrict__ counts) {
  int e = blockIdx.x * blockDim.x + threadIdx.x;
  if (e < NE) atomicAdd(&counts[ei[NE + e]], 1);
}
__global__ void k_scan(const int* __restrict__ counts, int* __restrict__ cursor) {
  __shared__ int buf[1024];
  __shared__ int carry;
  int tid = threadIdx.x;
  if (tid == 0) carry = 0;
  __syncthreads();
  for (int base = 0; base < NN; base += 1024) {
    int i = base + tid;
    int v = (i < NN) ? counts[i] : 0;
    buf[tid] = v;
    __syncthreads();
    for (int off = 1; off < 1024; off <<= 1) {
      int t = (tid >= off) ? buf[tid - off] : 0;
      __syncthreads();
      buf[tid] += t;
      __syncthreads();
    }
    int incl = buf[tid];
    int excl = incl - v + carry;
    if (i < NN) cursor[i] = excl;
    __syncthreads();
    if (tid == 1023) carry += incl;
    __syncthreads();
  }
}
__global__ void k_place(const int* __restrict__ ei, int* __restrict__ cursor,
                        int* __restrict__ perm) {
  int e = blockIdx.x * blockDim.x + threadIdx.x;
  if (e < NE) {
    int d = ei[NE + e];
    int p = atomicAdd(&cursor[d], 1);
    perm[p] = e;
  }
}

// ---------------- edge precompute: sorted src/dst/tv only ----------------
__global__ void k_edge(const int* __restrict__ ei, const int* __restrict__ perm,
                       const float* __restrict__ pos,
                       int* __restrict__ srcS, int* __restrict__ dstS,
                       float* __restrict__ tvS) {
  int p = blockIdx.x * 256 + threadIdx.x;
  if (p >= NE) return;
  int e = perm[p];
  int s = ei[e], t = ei[NE + e];
  srcS[p] = s; dstS[p] = t;
  float dx = pos[3*s]   - pos[3*t];
  float dy = pos[3*s+1] - pos[3*t+1];
  float dz = pos[3*s+2] - pos[3*t+2];
  float d = sqrtf(dx*dx + dy*dy + dz*dz);
  tvS[p] = expf(-d);
}

// ---------------- filter tables: F_t(tv) in R^128, bf16, PERMUTED cols ----------------
// t=0: (attr@npW + npb)*C ; t=1..6: (silu(attr@W1+b1)@W2 + b2)*C
__global__ __launch_bounds__(256) void k_tbuild(
    const float* __restrict__ means, const float* __restrict__ betas,
    const float* __restrict__ npW, const float* __restrict__ npb,
    const float* __restrict__ W1, const float* __restrict__ b1,
    const float* __restrict__ W2, const float* __restrict__ b2,
    u16* __restrict__ tb)
{
  int t  = blockIdx.x / (TBINS / 32);
  int j0 = (blockIdx.x % (TBINS / 32)) * 32;
  __shared__ float sAttr[32][52];
  __shared__ float sCut[32];
  __shared__ float sT[32][132];
  int tid = threadIdx.x;
  float tv0 = expf(-5.f);
  float dtv = (1.f - tv0) / (float)(TBINS - 1);
  for (int idx = tid; idx < 32 * RB; idx += 256) {
    int r = idx / RB, k = idx % RB;
    float tv = tv0 + (j0 + r) * dtv;
    float d = -logf(tv);
    float C = 0.5f * (cosf(d * 0.628318530717958647692f) + 1.f);
    if (d >= 5.f) C = 0.f;
    float diff = tv - means[k];
    sAttr[r][k] = C * expf(-betas[k] * diff * diff);
    if (k == 0) sCut[r] = C;
  }
  __syncthreads();
  int g = tid >> 5, c0 = (tid & 31) * 4, eb = g * 4;
  float acc[4][4];
  #pragma unroll
  for (int i = 0; i < 4; ++i)
    for (int j = 0; j < 4; ++j) acc[i][j] = 0.f;
  const float* Wa = (t == 0) ? npW : (W1 + (size_t)(t - 1) * RB * H);
  for (int k = 0; k < RB; ++k) {
    float4 wv = *(const float4*)&Wa[(size_t)k * H + c0];
    #pragma unroll
    for (int i = 0; i < 4; ++i) {
      float a = sAttr[eb + i][k];
      acc[i][0] += a * wv.x; acc[i][1] += a * wv.y;
      acc[i][2] += a * wv.z; acc[i][3] += a * wv.w;
    }
  }
  size_t obase = (size_t)t * TBINS * H;
  int pb = (c0 & 15) * 8 + (c0 >> 4);
  if (t == 0) {
    float4 b4 = *(const float4*)&npb[c0];
    float bvA[4] = {b4.x, b4.y, b4.z, b4.w};
    #pragma unroll
    for (int i = 0; i < 4; ++i) {
      float Cv = sCut[eb + i];
      size_t rb = obase + (size_t)(j0 + eb + i) * H;
      #pragma unroll
      for (int j = 0; j < 4; ++j)
        tb[rb + pb + 8 * j] = f2b((acc[i][j] + bvA[j]) * Cv);
    }
  } else {
    float4 b4 = *(const float4*)&b1[(size_t)(t - 1) * H + c0];
    float bvA[4] = {b4.x, b4.y, b4.z, b4.w};
    #pragma unroll
    for (int i = 0; i < 4; ++i) {
      #pragma unroll
      for (int j = 0; j < 4; ++j) {
        float v = acc[i][j] + bvA[j];
        sT[eb + i][c0 + j] = v / (1.f + __expf(-v));
      }
    }
    __syncthreads();
    #pragma unroll
    for (int i = 0; i < 4; ++i)
      for (int j = 0; j < 4; ++j) acc[i][j] = 0.f;
    const float* Wb = W2 + (size_t)(t - 1) * H * H;
    for (int k = 0; k < H; ++k) {
      float4 wv = *(const float4*)&Wb[(size_t)k * H + c0];
      #pragma unroll
      for (int i = 0; i < 4; ++i) {
        float a = sT[eb + i][k];
        acc[i][0] += a * wv.x; acc[i][1] += a * wv.y;
        acc[i][2] += a * wv.z; acc[i][3] += a * wv.w;
      }
    }
    float4 b24 = *(const float4*)&b2[(size_t)(t - 1) * H + c0];
    float bvB[4] = {b24.x, b24.y, b24.z, b24.w};
    #pragma unroll
    for (int i = 0; i < 4; ++i) {
      float Cv = sCut[eb + i];
      size_t rb = obase + (size_t)(j0 + eb + i) * H;
      #pragma unroll
      for (int j = 0; j < 4; ++j)
        tb[rb + pb + 8 * j] = f2b((acc[i][j] + bvB[j]) * Cv);
    }
  }
}

// x f32 natural; xn bf16 PERMUTED; agg (natural) zero-init
__global__ void k_embed(const int* __restrict__ z, const float* __restrict__ emb,
                        const float* __restrict__ nemb,
                        float* __restrict__ x, u16* __restrict__ xnb,
                        float* __restrict__ aggz) {
  int i = blockIdx.x * blockDim.x + threadIdx.x;
  if (i >= NN * H) return;
  int n = i >> 7, c = i & (H - 1);
  long o = (long)z[n] * H + c;
  x[i] = emb[o];
  xnb[(size_t)n * H + ((c & 15) * 8 + (c >> 4))] = f2b(nemb[o]);
  aggz[i] = 0.f;
}

// ---------------- edge scatter: wf = interp(tb, tv); agg[dst] += wf * h[src] ----------------
// 16 lanes/edge (8 ch each); each 16-lane group walks 16 contiguous dst-sorted edges
__global__ __launch_bounds__(256) void k_es(
    const int* __restrict__ srcS, const int* __restrict__ dstS,
    const float* __restrict__ tvS, const u16* __restrict__ tb,
    const u16* __restrict__ hsrc, float* __restrict__ agg, int maskSelf)
{
  int tid = threadIdx.x;
  int lane = tid & 63, wv = tid >> 6;
  int r16 = lane & 15, g4 = lane >> 4;
  int g16 = g4 * 16;
  long ebase = (long)blockIdx.x * 256 + wv * 64 + g16;
  int srcR = srcS[ebase + r16];
  int dstR = dstS[ebase + r16];
  float tvR = tvS[ebase + r16];
  float tv0 = expf(-5.f);
  float inv = (float)(TBINS - 1) / (1.f - tv0);
  float vsum[8];
  #pragma unroll
  for (int ct = 0; ct < 8; ++ct) vsum[ct] = 0.f;
  int pdst = -1;
  // pipeline stage: current edge
  int sC = __shfl(srcR, g16, 64);
  int dC = __shfl(dstR, g16, 64);
  float tvC = __shfl(tvR, g16, 64);
  short8v hvC = *(const short8v*)&hsrc[(size_t)sC * H + r16 * 8];
  float uC = fminf(fmaxf((tvC - tv0) * inv, 0.f), (float)(TBINS - 1) - 1e-3f);
  int jC = (int)uC; float wC = uC - (float)jC;
  short8v loC = *(const short8v*)&tb[(size_t)jC * H + r16 * 8];
  short8v hiC = *(const short8v*)&tb[(size_t)(jC + 1) * H + r16 * 8];
  for (int i = 0; i < 16; ++i) {
    int sN = sC, dN = dC; short8v hvN = hvC, loN = loC, hiN = hiC; float wN = wC;
    if (i < 15) {
      sN = __shfl(srcR, g16 + i + 1, 64);
      dN = __shfl(dstR, g16 + i + 1, 64);
      float tvN = __shfl(tvR, g16 + i + 1, 64);
      hvN = *(const short8v*)&hsrc[(size_t)sN * H + r16 * 8];
      float u = fminf(fmaxf((tvN - tv0) * inv, 0.f), (float)(TBINS - 1) - 1e-3f);
      int jN = (int)u; wN = u - (float)jN;
      loN = *(const short8v*)&tb[(size_t)jN * H + r16 * 8];
      hiN = *(const short8v*)&tb[(size_t)(jN + 1) * H + r16 * 8];
    }
    float m = (maskSelf && sC == dC) ? 0.f : 1.f;
    if (dC != pdst) {
      if (pdst >= 0) {
        float* ap = agg + (size_t)pdst * H + r16;
        #pragma unroll
        for (int ct = 0; ct < 8; ++ct) atomicAdd(ap + ct * 16, vsum[ct]);
      }
      #pragma unroll
      for (int ct = 0; ct < 8; ++ct) vsum[ct] = 0.f;
      pdst = dC;
    }
    #pragma unroll
    for (int ct = 0; ct < 8; ++ct) {
      float lo = b2f((u16)loC[ct]);
      float hi = b2f((u16)hiC[ct]);
      float wf = lo + wC * (hi - lo);
      vsum[ct] += wf * m * b2f((u16)hvC[ct]);
    }
    sC = sN; dC = dN; hvC = hvN; loC = loN; hiC = hiN; wC = wN;
  }
  if (pdst >= 0) {
    float* ap = agg + (size_t)pdst * H + r16;
    #pragma unroll
    for (int ct = 0; ct < 8; ++ct) atomicAdd(ap + ct * 16, vsum[ct]);
  }
}

// ---------------- combine: x = [x||agg]@cW + cb;  h0 = x@l1W0 (bf16 permuted) ----------------
__global__ __launch_bounds__(256) void k_combine(
    const float* __restrict__ xb, float* __restrict__ ag,
    const float* __restrict__ cW, const float* __restrict__ cb,
    const float* __restrict__ l1W0, float* __restrict__ xout,
    u16* __restrict__ hb)
{
  __shared__ float sX[32][132];
  __shared__ float sG[32][132];
  int tid = threadIdx.x;
  int n0 = blockIdx.x * 32;
  #pragma unroll
  for (int j = 0; j < 4; ++j) {
    int f4 = tid + j * 256;
    int r = f4 >> 5, c4 = f4 & 31;
    *(float4*)&sX[r][c4 * 4] = *(const float4*)&xb[(size_t)(n0 + r) * H + c4 * 4];
    *(float4*)&sG[r][c4 * 4] = *(const float4*)&ag[(size_t)(n0 + r) * H + c4 * 4];
    *(float4*)&ag[(size_t)(n0 + r) * H + c4 * 4] = make_float4(0.f, 0.f, 0.f, 0.f);
  }
  __syncthreads();
  int g = tid >> 5;
  int c0 = (tid & 31) * 4;
  int eb = g * 4;
  float acc[4][4];
  #pragma unroll
  for (int i = 0; i < 4; ++i)
    for (int j = 0; j < 4; ++j) acc[i][j] = 0.f;
  for (int k = 0; k < H; ++k) {
    float4 wv = *(const float4*)&cW[(size_t)k * H + c0];
    #pragma unroll
    for (int i = 0; i < 4; ++i) {
      float a = sX[eb + i][k];
      acc[i][0] += a * wv.x; acc[i][1] += a * wv.y;
      acc[i][2] += a * wv.z; acc[i][3] += a * wv.w;
    }
  }
  for (int k = 0; k < H; ++k) {
    float4 wv = *(const float4*)&cW[(size_t)(H + k) * H + c0];
    #pragma unroll
    for (int i = 0; i < 4; ++i) {
      float a = sG[eb + i][k];
      acc[i][0] += a * wv.x; acc[i][1] += a * wv.y;
      acc[i][2] += a * wv.z; acc[i][3] += a * wv.w;
    }
  }
  float4 bv = *(const float4*)&cb[c0];
  __syncthreads();
  #pragma unroll
  for (int i = 0; i < 4; ++i) {
    int n = n0 + eb + i;
    float o0 = acc[i][0] + bv.x, o1 = acc[i][1] + bv.y;
    float o2 = acc[i][2] + bv.z, o3 = acc[i][3] + bv.w;
    *(float4*)&xout[(size_t)n * H + c0] = make_float4(o0, o1, o2, o3);
    sX[eb + i][c0] = o0; sX[eb + i][c0+1] = o1;
    sX[eb + i][c0+2] = o2; sX[eb + i][c0+3] = o3;
  }
  __syncthreads();
  #pragma unroll
  for (int i = 0; i < 4; ++i)
    for (int j = 0; j < 4; ++j) acc[i][j] = 0.f;
  for (int k = 0; k < H; ++k) {
    float4 wv = *(const float4*)&l1W0[(size_t)k * H + c0];
    #pragma unroll
    for (int i = 0; i < 4; ++i) {
      float a = sX[eb + i][k];
      acc[i][0] += a * wv.x; acc[i][1] += a * wv.y;
      acc[i][2] += a * wv.z; acc[i][3] += a * wv.w;
    }
  }
  int pbase = (c0 & 15) * 8 + (c0 >> 4);
  #pragma unroll
  for (int i = 0; i < 4; ++i) {
    int n = n0 + eb + i;
    #pragma unroll
    for (int j = 0; j < 4; ++j)
      hb[(size_t)n * H + pbase + 8 * j] = f2b(acc[i][j]);
  }
}

// ---------------- fused lin2+lin (+next-layer lin1) ----------------
__global__ __launch_bounds__(256) void k_gemmF2(
    float* __restrict__ A, const float* __restrict__ W2,
    const float* __restrict__ b2, const float* __restrict__ W3,
    const float* __restrict__ b3, const float* __restrict__ xin,
    float* __restrict__ xout, const float* __restrict__ l1Wn,
    u16* __restrict__ hb)
{
  __shared__ float sA[32][132];
  __shared__ float sT[32][132];
  int tid = threadIdx.x;
  int n0 = blockIdx.x * 32;
  #pragma unroll
  for (int j = 0; j < 4; ++j) {
    int f4 = tid + j * 256;
    int r = f4 >> 5, c4 = f4 & 31;
    *(float4*)&sA[r][c4 * 4] = *(const float4*)&A[(size_t)(n0 + r) * H + c4 * 4];
    *(float4*)&A[(size_t)(n0 + r) * H + c4 * 4] = make_float4(0.f, 0.f, 0.f, 0.f);
  }
  __syncthreads();
  int g = tid >> 5;
  int c0 = (tid & 31) * 4;
  int eb = g * 4;
  float acc[4][4];
  #pragma unroll
  for (int i = 0; i < 4; ++i)
    for (int j = 0; j < 4; ++j) acc[i][j] = 0.f;
  for (int k = 0; k < H; ++k) {
    float4 wv = *(const float4*)&W2[(size_t)k * H + c0];
    #pragma unroll
    for (int i = 0; i < 4; ++i) {
      float a = sA[eb + i][k];
      acc[i][0] += a * wv.x; acc[i][1] += a * wv.y;
      acc[i][2] += a * wv.z; acc[i][3] += a * wv.w;
    }
  }
  float4 bv2 = *(const float4*)&b2[c0];
  #pragma unroll
  for (int i = 0; i < 4; ++i) {
    float t0 = acc[i][0] + bv2.x, t1 = acc[i][1] + bv2.y;
    float t2 = acc[i][2] + bv2.z, t3 = acc[i][3] + bv2.w;
    sT[eb + i][c0 + 0] = t0 / (1.f + __expf(-t0));
    sT[eb + i][c0 + 1] = t1 / (1.f + __expf(-t1));
    sT[eb + i][c0 + 2] = t2 / (1.f + __expf(-t2));
    sT[eb + i][c0 + 3] = t3 / (1.f + __expf(-t3));
  }
  __syncthreads();
  #pragma unroll
  for (int i = 0; i < 4; ++i)
    for (int j = 0; j < 4; ++j) acc[i][j] = 0.f;
  for (int k = 0; k < H; ++k) {
    float4 wv = *(const float4*)&W3[(size_t)k * H + c0];
    #pragma unroll
    for (int i = 0; i < 4; ++i) {
      float a = sT[eb + i][k];
      acc[i][0] += a * wv.x; acc[i][1] += a * wv.y;
      acc[i][2] += a * wv.z; acc[i][3] += a * wv.w;
    }
  }
  float4 bv3 = *(const float4*)&b3[c0];
  #pragma unroll
  for (int i = 0; i < 4; ++i) {
    int n = n0 + eb + i;
    float4 xv = *(const float4*)&xin[(size_t)n * H + c0];
    float o0 = xv.x + acc[i][0] + bv3.x, o1 = xv.y + acc[i][1] + bv3.y;
    float o2 = xv.z + acc[i][2] + bv3.z, o3 = xv.w + acc[i][3] + bv3.w;
    *(float4*)&xout[(size_t)n * H + c0] = make_float4(o0, o1, o2, o3);
    sA[eb + i][c0] = o0; sA[eb + i][c0+1] = o1;
    sA[eb + i][c0+2] = o2; sA[eb + i][c0+3] = o3;
  }
  if (l1Wn) {
    __syncthreads();
    #pragma unroll
    for (int i = 0; i < 4; ++i)
      for (int j = 0; j < 4; ++j) acc[i][j] = 0.f;
    for (int k = 0; k < H; ++k) {
      float4 wv = *(const float4*)&l1Wn[(size_t)k * H + c0];
      #pragma unroll
      for (int i = 0; i < 4; ++i) {
        float a = sA[eb + i][k];
        acc[i][0] += a * wv.x; acc[i][1] += a * wv.y;
        acc[i][2] += a * wv.z; acc[i][3] += a * wv.w;
      }
    }
    int pbase = (c0 & 15) * 8 + (c0 >> 4);
    #pragma unroll
    for (int i = 0; i < 4; ++i) {
      int n = n0 + eb + i;
      #pragma unroll
      for (int j = 0; j < 4; ++j)
        hb[(size_t)n * H + pbase + 8 * j] = f2b(acc[i][j]);
    }
  }
}

// ---------------- launcher ----------------
extern "C" void kernel_launch(void* const* d_in, const int* in_sizes, int n_in,
                              void* d_out, int out_size, void* d_ws, size_t ws_size,
                              hipStream_t stream) {
  int bo = (n_in >= 4 && in_sizes[3] == NN) ? 0 : -1;  // batch present?
  const int*   z     = (const int*)d_in[0];
  const float* pos   = (const float*)d_in[1];
  const int*   ei    = (const int*)d_in[2];
  const float* emb   = (const float*)d_in[4 + bo];
  const float* nemb  = (const float*)d_in[5 + bo];
  const float* npW   = (const float*)d_in[6 + bo];
  const float* npb   = (const float*)d_in[7 + bo];
  const float* cW    = (const float*)d_in[8 + bo];
  const float* cb    = (const float*)d_in[9 + bo];
  const float* means = (const float*)d_in[10 + bo];
  const float* betas = (const float*)d_in[11 + bo];
  const float* W1    = (const float*)d_in[12 + bo];
  const float* b1    = (const float*)d_in[13 + bo];
  const float* W2    = (const float*)d_in[14 + bo];
  const float* b2    = (const float*)d_in[15 + bo];
  const float* l1W   = (const float*)d_in[16 + bo];
  const float* l2W   = (const float*)d_in[17 + bo];
  const float* l2b   = (const float*)d_in[18 + bo];
  const float* lW    = (const float*)d_in[19 + bo];
  const float* lb    = (const float*)d_in[20 + bo];

  char* w = (char*)d_ws;
  auto alloc = [&](size_t bytes) { char* p = w; w += (bytes + 255) & ~(size_t)255; return p; };
  int*   counts = (int*)  alloc((size_t)NN * 4);
  int*   cursor = (int*)  alloc((size_t)NN * 4);
  int*   perm   = (int*)  alloc((size_t)NE * 4);
  int*   srcS   = (int*)  alloc((size_t)NE * 4);
  int*   dstS   = (int*)  alloc((size_t)NE * 4);
  float* tvS    = (float*)alloc((size_t)NE * 4);
  u16*   tb     = (u16*)  alloc((size_t)7 * TBINS * H * 2);
  float* xbuf   = (float*)alloc((size_t)NN * H * 4);
  float* agg    = (float*)alloc((size_t)NN * H * 4);
  u16*   xnb    = (u16*)  alloc((size_t)NN * H * 2);
  u16*   hbuf   = (u16*)  alloc((size_t)NN * H * 2);

  dim3 b256(256);
  int gE256 = (NE + 255) / 256;        // 2500
  int gNH   = (NN * H + 255) / 256;    // 10000
  int gES   = NE / 256;                // 2500
  int gG    = NN / 32;                 // 625
  int gTB   = 7 * (TBINS / 32);        // 896

  k_zero_i32<<<(NN + 255) / 256, b256, 0, stream>>>(counts, NN);
  k_hist<<<gE256, b256, 0, stream>>>(ei, counts);
  k_scan<<<1, 1024, 0, stream>>>(counts, cursor);
  k_place<<<gE256, b256, 0, stream>>>(ei, cursor, perm);
  k_edge<<<gE256, b256, 0, stream>>>(ei, perm, pos, srcS, dstS, tvS);
  k_tbuild<<<gTB, b256, 0, stream>>>(means, betas, npW, npb, W1, b1, W2, b2, tb);
  k_embed<<<gNH, b256, 0, stream>>>(z, emb, nemb, xbuf, xnb, agg);

  // neighbor embedding scatter (table 0, self-mask on)
  k_es<<<gES, b256, 0, stream>>>(srcS, dstS, tvS, tb, xnb, agg, 1);
  k_combine<<<gG, b256, 0, stream>>>(xbuf, agg, cW, cb, l1W, xbuf, hbuf);

  for (int l = 0; l < NL; ++l) {
    k_es<<<gES, b256, 0, stream>>>(srcS, dstS, tvS,
                                   tb + (size_t)(1 + l) * TBINS * H,
                                   hbuf, agg, 0);
    const float* l1Wn = (l + 1 < NL) ? (l1W + (size_t)(l + 1) * H * H) : nullptr;
    float* xo = (l == NL - 1) ? (float*)d_out : xbuf;
    k_gemmF2<<<gG, b256, 0, stream>>>(agg, l2W + (size_t)l * H * H, l2b + (size_t)l * H,
                                      lW + (size_t)l * H * H, lb + (size_t)l * H,
                                      xbuf, xo, l1Wn, hbuf);
  }
}

// Round 14
// 788.343 us; speedup vs baseline: 4.4694x; 1.0475x over previous
//
#include <hip/hip_runtime.h>
#include <hip/hip_bf16.h>
#include <math.h>

#define NN 20000
#define NE 640000
#define H  128
#define RB 50
#define NL 6
#define TBINS 4096

typedef unsigned short u16;
typedef __attribute__((ext_vector_type(8))) short short8v;
typedef __attribute__((ext_vector_type(4))) float f32x4;

// gather permutation (h/xn/tables): col c -> slot (c&15)*8 + (c>>4)
__device__ __forceinline__ u16 f2b(float v) {
  unsigned x = __float_as_uint(v);
  unsigned r = (x + 0x7FFFu + ((x >> 16) & 1u)) >> 16;
  return (u16)r;
}
__device__ __forceinline__ float b2f(u16 u) {
  return __uint_as_float(((unsigned int)u) << 16);
}

// ---------------- sort machinery ----------------
__global__ void k_zero_i32(int* __restrict__ p, int n) {
  int i = blockIdx.x * blockDim.x + threadIdx.x;
  if (i < n) p[i] = 0;
}
__global__ void k_hist(const int* __restrict__ ei, int* __restrict__ counts) {
  int e = blockIdx.x * blockDim.x + threadIdx.x;
  if (e < NE) atomicAdd(&counts[ei[NE + e]], 1);
}
__global__ void k_scan(const int* __restrict__ counts, int* __restrict__ cursor) {
  __shared__ int buf[1024];
  __shared__ int carry;
  int tid = threadIdx.x;
  if (tid == 0) carry = 0;
  __syncthreads();
  for (int base = 0; base < NN; base += 1024) {
    int i = base + tid;
    int v = (i < NN) ? counts[i] : 0;
    buf[tid] = v;
    __syncthreads();
    for (int off = 1; off < 1024; off <<= 1) {
      int t = (tid >= off) ? buf[tid - off] : 0;
      __syncthreads();
      buf[tid] += t;
      __syncthreads();
    }
    int incl = buf[tid];
    int excl = incl - v + carry;
    if (i < NN) cursor[i] = excl;
    __syncthreads();
    if (tid == 1023) carry += incl;
    __syncthreads();
  }
}
__global__ void k_place(const int* __restrict__ ei, int* __restrict__ cursor,
                        int* __restrict__ perm) {
  int e = blockIdx.x * blockDim.x + threadIdx.x;
  if (e < NE) {
    int d = ei[NE + e];
    int p = atomicAdd(&cursor[d], 1);
    perm[p] = e;
  }
}

// ---------------- edge precompute: sorted src/dst/tv only ----------------
__global__ void k_edge(const int* __restrict__ ei, const int* __restrict__ perm,
                       const float* __restrict__ pos,
                       int* __restrict__ srcS, int* __restrict__ dstS,
                       float* __restrict__ tvS) {
  int p = blockIdx.x * 256 + threadIdx.x;
  if (p >= NE) return;
  int e = perm[p];
  int s = ei[e], t = ei[NE + e];
  srcS[p] = s; dstS[p] = t;
  float dx = pos[3*s]   - pos[3*t];
  float dy = pos[3*s+1] - pos[3*t+1];
  float dz = pos[3*s+2] - pos[3*t+2];
  float d = sqrtf(dx*dx + dy*dy + dz*dz);
  tvS[p] = expf(-d);
}

// ---------------- filter tables: F_t(tv) in R^128, bf16, PERMUTED cols ----------------
__global__ __launch_bounds__(256) void k_tbuild(
    const float* __restrict__ means, const float* __restrict__ betas,
    const float* __restrict__ npW, const float* __restrict__ npb,
    const float* __restrict__ W1, const float* __restrict__ b1,
    const float* __restrict__ W2, const float* __restrict__ b2,
    u16* __restrict__ tb)
{
  int t  = blockIdx.x / (TBINS / 32);
  int j0 = (blockIdx.x % (TBINS / 32)) * 32;
  __shared__ float sAttr[32][52];
  __shared__ float sCut[32];
  __shared__ float sT[32][132];
  int tid = threadIdx.x;
  float tv0 = expf(-5.f);
  float dtv = (1.f - tv0) / (float)(TBINS - 1);
  for (int idx = tid; idx < 32 * RB; idx += 256) {
    int r = idx / RB, k = idx % RB;
    float tv = tv0 + (j0 + r) * dtv;
    float d = -logf(tv);
    float C = 0.5f * (cosf(d * 0.628318530717958647692f) + 1.f);
    if (d >= 5.f) C = 0.f;
    float diff = tv - means[k];
    sAttr[r][k] = C * expf(-betas[k] * diff * diff);
    if (k == 0) sCut[r] = C;
  }
  __syncthreads();
  int g = tid >> 5, c0 = (tid & 31) * 4, eb = g * 4;
  float acc[4][4];
  #pragma unroll
  for (int i = 0; i < 4; ++i)
    for (int j = 0; j < 4; ++j) acc[i][j] = 0.f;
  const float* Wa = (t == 0) ? npW : (W1 + (size_t)(t - 1) * RB * H);
  for (int k = 0; k < RB; ++k) {
    float4 wv = *(const float4*)&Wa[(size_t)k * H + c0];
    #pragma unroll
    for (int i = 0; i < 4; ++i) {
      float a = sAttr[eb + i][k];
      acc[i][0] += a * wv.x; acc[i][1] += a * wv.y;
      acc[i][2] += a * wv.z; acc[i][3] += a * wv.w;
    }
  }
  size_t obase = (size_t)t * TBINS * H;
  int pb = (c0 & 15) * 8 + (c0 >> 4);
  if (t == 0) {
    float4 b4 = *(const float4*)&npb[c0];
    float bvA[4] = {b4.x, b4.y, b4.z, b4.w};
    #pragma unroll
    for (int i = 0; i < 4; ++i) {
      float Cv = sCut[eb + i];
      size_t rb = obase + (size_t)(j0 + eb + i) * H;
      #pragma unroll
      for (int j = 0; j < 4; ++j)
        tb[rb + pb + 8 * j] = f2b((acc[i][j] + bvA[j]) * Cv);
    }
  } else {
    float4 b4 = *(const float4*)&b1[(size_t)(t - 1) * H + c0];
    float bvA[4] = {b4.x, b4.y, b4.z, b4.w};
    #pragma unroll
    for (int i = 0; i < 4; ++i) {
      #pragma unroll
      for (int j = 0; j < 4; ++j) {
        float v = acc[i][j] + bvA[j];
        sT[eb + i][c0 + j] = v / (1.f + __expf(-v));
      }
    }
    __syncthreads();
    #pragma unroll
    for (int i = 0; i < 4; ++i)
      for (int j = 0; j < 4; ++j) acc[i][j] = 0.f;
    const float* Wb = W2 + (size_t)(t - 1) * H * H;
    for (int k = 0; k < H; ++k) {
      float4 wv = *(const float4*)&Wb[(size_t)k * H + c0];
      #pragma unroll
      for (int i = 0; i < 4; ++i) {
        float a = sT[eb + i][k];
        acc[i][0] += a * wv.x; acc[i][1] += a * wv.y;
        acc[i][2] += a * wv.z; acc[i][3] += a * wv.w;
      }
    }
    float4 b24 = *(const float4*)&b2[(size_t)(t - 1) * H + c0];
    float bvB[4] = {b24.x, b24.y, b24.z, b24.w};
    #pragma unroll
    for (int i = 0; i < 4; ++i) {
      float Cv = sCut[eb + i];
      size_t rb = obase + (size_t)(j0 + eb + i) * H;
      #pragma unroll
      for (int j = 0; j < 4; ++j)
        tb[rb + pb + 8 * j] = f2b((acc[i][j] + bvB[j]) * Cv);
    }
  }
}

// ---------------- node-GEMM weight transpose to bf16 [n][k] stride 136 ----------------
// a=0: l2W, a=1: lW, a=2: l1W  (all [6][128][128] k-major)
__global__ void k_prepw2(const float* __restrict__ l2W, const float* __restrict__ lW,
                         const float* __restrict__ l1W, u16* __restrict__ wt) {
  int i = blockIdx.x * 256 + threadIdx.x;
  if (i >= 3 * NL * 128 * 136) return;
  int a = i / (NL * 128 * 136);
  int r = i % (NL * 128 * 136);
  int l = r / (128 * 136);
  int r2 = r % (128 * 136);
  int n = r2 / 136, k = r2 % 136;
  const float* src = (a == 0) ? l2W : (a == 1) ? lW : l1W;
  wt[i] = (k < H) ? f2b(src[(size_t)l * H * H + (size_t)k * H + n]) : (u16)0;
}

// x f32 natural; xn bf16 PERMUTED; agg (natural) zero-init
__global__ void k_embed(const int* __restrict__ z, const float* __restrict__ emb,
                        const float* __restrict__ nemb,
                        float* __restrict__ x, u16* __restrict__ xnb,
                        float* __restrict__ aggz) {
  int i = blockIdx.x * blockDim.x + threadIdx.x;
  if (i >= NN * H) return;
  int n = i >> 7, c = i & (H - 1);
  long o = (long)z[n] * H + c;
  x[i] = emb[o];
  xnb[(size_t)n * H + ((c & 15) * 8 + (c >> 4))] = f2b(nemb[o]);
  aggz[i] = 0.f;
}

// ---------------- edge scatter: depth-3 pipelined table interp + gather ----------------
__global__ __launch_bounds__(256) void k_es(
    const int* __restrict__ srcS, const int* __restrict__ dstS,
    const float* __restrict__ tvS, const u16* __restrict__ tb,
    const u16* __restrict__ hsrc, float* __restrict__ agg, int maskSelf)
{
  int tid = threadIdx.x;
  int lane = tid & 63, wv = tid >> 6;
  int r16 = lane & 15, g4 = lane >> 4;
  int g16 = g4 * 16;
  long ebase = (long)blockIdx.x * 256 + wv * 64 + g16;
  int srcR = srcS[ebase + r16];
  int dstR = dstS[ebase + r16];
  float tvR = tvS[ebase + r16];
  float tv0 = expf(-5.f);
  float inv = (float)(TBINS - 1) / (1.f - tv0);
  float vsum[8];
  #pragma unroll
  for (int ct = 0; ct < 8; ++ct) vsum[ct] = 0.f;
  int pdst = -1;
  int A_s, A_d, B_s, B_d, C_s, C_d;
  float A_w, B_w, C_w;
  short8v A_hv, A_lo, A_hi, B_hv, B_lo, B_hi, C_hv, C_lo, C_hi;
#define ISSUE(ii, P) { \
    P##_s = __shfl(srcR, g16 + (ii), 64); \
    P##_d = __shfl(dstR, g16 + (ii), 64); \
    float tvv = __shfl(tvR, g16 + (ii), 64); \
    P##_hv = *(const short8v*)&hsrc[(size_t)P##_s * H + r16 * 8]; \
    float u = fminf(fmaxf((tvv - tv0) * inv, 0.f), (float)(TBINS - 1) - 1e-3f); \
    int jj = (int)u; P##_w = u - (float)jj; \
    P##_lo = *(const short8v*)&tb[(size_t)jj * H + r16 * 8]; \
    P##_hi = *(const short8v*)&tb[(size_t)(jj + 1) * H + r16 * 8]; }
#define CONSUME(P) { \
    float m = (maskSelf && P##_s == P##_d) ? 0.f : 1.f; \
    if (P##_d != pdst) { \
      if (pdst >= 0) { \
        float* ap = agg + (size_t)pdst * H + r16; \
        _Pragma("unroll") \
        for (int ct = 0; ct < 8; ++ct) atomicAdd(ap + ct * 16, vsum[ct]); \
      } \
      _Pragma("unroll") \
      for (int ct = 0; ct < 8; ++ct) vsum[ct] = 0.f; \
      pdst = P##_d; \
    } \
    _Pragma("unroll") \
    for (int ct = 0; ct < 8; ++ct) { \
      float lo = b2f((u16)P##_lo[ct]); \
      float hi = b2f((u16)P##_hi[ct]); \
      vsum[ct] += (lo + P##_w * (hi - lo)) * m * b2f((u16)P##_hv[ct]); \
    } }
  ISSUE(0, A); ISSUE(1, B); ISSUE(2, C);
  #pragma unroll
  for (int i = 0; i < 16; ++i) {
    int ph = i % 3;
    if (ph == 0) { CONSUME(A); if (i + 3 < 16) ISSUE(i + 3, A); }
    else if (ph == 1) { CONSUME(B); if (i + 3 < 16) ISSUE(i + 3, B); }
    else { CONSUME(C); if (i + 3 < 16) ISSUE(i + 3, C); }
  }
#undef ISSUE
#undef CONSUME
  if (pdst >= 0) {
    float* ap = agg + (size_t)pdst * H + r16;
    #pragma unroll
    for (int ct = 0; ct < 8; ++ct) atomicAdd(ap + ct * 16, vsum[ct]);
  }
}

// ---------------- combine: x = [x||agg]@cW + cb;  h0 = x@l1W0 (bf16 permuted) ----------------
__global__ __launch_bounds__(256) void k_combine(
    const float* __restrict__ xb, float* __restrict__ ag,
    const float* __restrict__ cW, const float* __restrict__ cb,
    const float* __restrict__ l1W0, float* __restrict__ xout,
    u16* __restrict__ hb)
{
  __shared__ float sX[32][132];
  __shared__ float sG[32][132];
  int tid = threadIdx.x;
  int n0 = blockIdx.x * 32;
  #pragma unroll
  for (int j = 0; j < 4; ++j) {
    int f4 = tid + j * 256;
    int r = f4 >> 5, c4 = f4 & 31;
    *(float4*)&sX[r][c4 * 4] = *(const float4*)&xb[(size_t)(n0 + r) * H + c4 * 4];
    *(float4*)&sG[r][c4 * 4] = *(const float4*)&ag[(size_t)(n0 + r) * H + c4 * 4];
    *(float4*)&ag[(size_t)(n0 + r) * H + c4 * 4] = make_float4(0.f, 0.f, 0.f, 0.f);
  }
  __syncthreads();
  int g = tid >> 5;
  int c0 = (tid & 31) * 4;
  int eb = g * 4;
  float acc[4][4];
  #pragma unroll
  for (int i = 0; i < 4; ++i)
    for (int j = 0; j < 4; ++j) acc[i][j] = 0.f;
  for (int k = 0; k < H; ++k) {
    float4 wv = *(const float4*)&cW[(size_t)k * H + c0];
    #pragma unroll
    for (int i = 0; i < 4; ++i) {
      float a = sX[eb + i][k];
      acc[i][0] += a * wv.x; acc[i][1] += a * wv.y;
      acc[i][2] += a * wv.z; acc[i][3] += a * wv.w;
    }
  }
  for (int k = 0; k < H; ++k) {
    float4 wv = *(const float4*)&cW[(size_t)(H + k) * H + c0];
    #pragma unroll
    for (int i = 0; i < 4; ++i) {
      float a = sG[eb + i][k];
      acc[i][0] += a * wv.x; acc[i][1] += a * wv.y;
      acc[i][2] += a * wv.z; acc[i][3] += a * wv.w;
    }
  }
  float4 bv = *(const float4*)&cb[c0];
  __syncthreads();
  #pragma unroll
  for (int i = 0; i < 4; ++i) {
    int n = n0 + eb + i;
    float o0 = acc[i][0] + bv.x, o1 = acc[i][1] + bv.y;
    float o2 = acc[i][2] + bv.z, o3 = acc[i][3] + bv.w;
    *(float4*)&xout[(size_t)n * H + c0] = make_float4(o0, o1, o2, o3);
    sX[eb + i][c0] = o0; sX[eb + i][c0+1] = o1;
    sX[eb + i][c0+2] = o2; sX[eb + i][c0+3] = o3;
  }
  __syncthreads();
  #pragma unroll
  for (int i = 0; i < 4; ++i)
    for (int j = 0; j < 4; ++j) acc[i][j] = 0.f;
  for (int k = 0; k < H; ++k) {
    float4 wv = *(const float4*)&l1W0[(size_t)k * H + c0];
    #pragma unroll
    for (int i = 0; i < 4; ++i) {
      float a = sX[eb + i][k];
      acc[i][0] += a * wv.x; acc[i][1] += a * wv.y;
      acc[i][2] += a * wv.z; acc[i][3] += a * wv.w;
    }
  }
  int pbase = (c0 & 15) * 8 + (c0 >> 4);
  #pragma unroll
  for (int i = 0; i < 4; ++i) {
    int n = n0 + eb + i;
    #pragma unroll
    for (int j = 0; j < 4; ++j)
      hb[(size_t)n * H + pbase + 8 * j] = f2b(acc[i][j]);
  }
}

// ---------------- MFMA node chain: x += silu(agg@W2+b2)@W3 + b3; hb = x@l1Wn ----------------
// 64 nodes/block, 4 waves; one barrier; weights bf16 [n][136] from global (L2)
__global__ __launch_bounds__(256) void k_gemmM(
    float* __restrict__ A, const u16* __restrict__ W2t, const float* __restrict__ b2,
    const u16* __restrict__ W3t, const float* __restrict__ b3,
    const float* __restrict__ xin, float* __restrict__ xout,
    const u16* __restrict__ l1Wnt, u16* __restrict__ hb)
{
  __shared__ __align__(16) u16 sA[64 * 136];
  __shared__ __align__(16) u16 sT[64 * 136];
  int tid = threadIdx.x;
  int lane = tid & 63, wv = tid >> 6;
  int r16 = lane & 15, g4 = lane >> 4;
  int n0 = blockIdx.x * 64;
  // stage agg -> bf16 sA; zero agg
  #pragma unroll
  for (int j = 0; j < 8; ++j) {
    int f4 = tid + j * 256;
    int r = f4 >> 5, c4 = f4 & 31;
    int n = n0 + r;
    float4 v = make_float4(0.f, 0.f, 0.f, 0.f);
    if (n < NN) {
      v = *(const float4*)&A[(size_t)n * H + c4 * 4];
      *(float4*)&A[(size_t)n * H + c4 * 4] = make_float4(0.f, 0.f, 0.f, 0.f);
    }
    unsigned lo = (unsigned)f2b(v.x) | ((unsigned)f2b(v.y) << 16);
    unsigned hi = (unsigned)f2b(v.z) | ((unsigned)f2b(v.w) << 16);
    *(unsigned*)&sA[r * 136 + c4 * 4]     = lo;
    *(unsigned*)&sA[r * 136 + c4 * 4 + 2] = hi;
  }
  __syncthreads();
  int wrow = wv * 16;
  // GEMM1: t = sA @ W2t
  f32x4 acc[8];
  #pragma unroll
  for (int ct = 0; ct < 8; ++ct) acc[ct] = (f32x4){0.f, 0.f, 0.f, 0.f};
  #pragma unroll
  for (int kt = 0; kt < 4; ++kt) {
    short8v aF = *(const short8v*)&sA[(wrow + r16) * 136 + kt * 32 + g4 * 8];
    #pragma unroll
    for (int ct = 0; ct < 8; ++ct) {
      short8v bF = *(const short8v*)&W2t[(ct * 16 + r16) * 136 + kt * 32 + g4 * 8];
      acc[ct] = __builtin_amdgcn_mfma_f32_16x16x32_bf16(aF, bF, acc[ct], 0, 0, 0);
    }
  }
  // silu + bias -> sT (wave-local rows)
  #pragma unroll
  for (int ct = 0; ct < 8; ++ct) {
    float bb = b2[ct * 16 + r16];
    #pragma unroll
    for (int r = 0; r < 4; ++r) {
      float v = acc[ct][r] + bb;
      v = v / (1.f + __expf(-v));
      sT[(wrow + g4 * 4 + r) * 136 + ct * 16 + r16] = f2b(v);
    }
  }
  // GEMM2: o = sT @ W3t
  #pragma unroll
  for (int ct = 0; ct < 8; ++ct) acc[ct] = (f32x4){0.f, 0.f, 0.f, 0.f};
  #pragma unroll
  for (int kt = 0; kt < 4; ++kt) {
    short8v aF = *(const short8v*)&sT[(wrow + r16) * 136 + kt * 32 + g4 * 8];
    #pragma unroll
    for (int ct = 0; ct < 8; ++ct) {
      short8v bF = *(const short8v*)&W3t[(ct * 16 + r16) * 136 + kt * 32 + g4 * 8];
      acc[ct] = __builtin_amdgcn_mfma_f32_16x16x32_bf16(aF, bF, acc[ct], 0, 0, 0);
    }
  }
  // residual add + write xout; re-stage x (bf16) into own sA rows
  #pragma unroll
  for (int ct = 0; ct < 8; ++ct) {
    float bb = b3[ct * 16 + r16];
    #pragma unroll
    for (int r = 0; r < 4; ++r) {
      int n = n0 + wrow + g4 * 4 + r;
      if (n < NN) {
        float o = acc[ct][r] + bb + xin[(size_t)n * H + ct * 16 + r16];
        xout[(size_t)n * H + ct * 16 + r16] = o;
        sA[(wrow + g4 * 4 + r) * 136 + ct * 16 + r16] = f2b(o);
      }
    }
  }
  if (!l1Wnt) return;
  // GEMM3: hb = xnew @ l1Wnt (hb permuted: one 16B store per row)
  #pragma unroll
  for (int ct = 0; ct < 8; ++ct) acc[ct] = (f32x4){0.f, 0.f, 0.f, 0.f};
  #pragma unroll
  for (int kt = 0; kt < 4; ++kt) {
    short8v aF = *(const short8v*)&sA[(wrow + r16) * 136 + kt * 32 + g4 * 8];
    #pragma unroll
    for (int ct = 0; ct < 8; ++ct) {
      short8v bF = *(const short8v*)&l1Wnt[(ct * 16 + r16) * 136 + kt * 32 + g4 * 8];
      acc[ct] = __builtin_amdgcn_mfma_f32_16x16x32_bf16(aF, bF, acc[ct], 0, 0, 0);
    }
  }
  #pragma unroll
  for (int r = 0; r < 4; ++r) {
    int n = n0 + wrow + g4 * 4 + r;
    if (n < NN) {
      short8v hv;
      #pragma unroll
      for (int ct = 0; ct < 8; ++ct) hv[ct] = (short)f2b(acc[ct][r]);
      *(short8v*)&hb[(size_t)n * H + r16 * 8] = hv;
    }
  }
}

// ---------------- launcher ----------------
extern "C" void kernel_launch(void* const* d_in, const int* in_sizes, int n_in,
                              void* d_out, int out_size, void* d_ws, size_t ws_size,
                              hipStream_t stream) {
  int bo = (n_in >= 4 && in_sizes[3] == NN) ? 0 : -1;  // batch present?
  const int*   z     = (const int*)d_in[0];
  const float* pos   = (const float*)d_in[1];
  const int*   ei    = (const int*)d_in[2];
  const float* emb   = (const float*)d_in[4 + bo];
  const float* nemb  = (const float*)d_in[5 + bo];
  const float* npW   = (const float*)d_in[6 + bo];
  const float* npb   = (const float*)d_in[7 + bo];
  const float* cW    = (const float*)d_in[8 + bo];
  const float* cb    = (const float*)d_in[9 + bo];
  const float* means = (const float*)d_in[10 + bo];
  const float* betas = (const float*)d_in[11 + bo];
  const float* W1    = (const float*)d_in[12 + bo];
  const float* b1    = (const float*)d_in[13 + bo];
  const float* W2    = (const float*)d_in[14 + bo];
  const float* b2    = (const float*)d_in[15 + bo];
  const float* l1W   = (const float*)d_in[16 + bo];
  const float* l2W   = (const float*)d_in[17 + bo];
  const float* l2b   = (const float*)d_in[18 + bo];
  const float* lW    = (const float*)d_in[19 + bo];
  const float* lb    = (const float*)d_in[20 + bo];

  char* w = (char*)d_ws;
  auto alloc = [&](size_t bytes) { char* p = w; w += (bytes + 255) & ~(size_t)255; return p; };
  int*   counts = (int*)  alloc((size_t)NN * 4);
  int*   cursor = (int*)  alloc((size_t)NN * 4);
  int*   perm   = (int*)  alloc((size_t)NE * 4);
  int*   srcS   = (int*)  alloc((size_t)NE * 4);
  int*   dstS   = (int*)  alloc((size_t)NE * 4);
  float* tvS    = (float*)alloc((size_t)NE * 4);
  u16*   tb     = (u16*)  alloc((size_t)7 * TBINS * H * 2);
  u16*   wt     = (u16*)  alloc((size_t)3 * NL * 128 * 136 * 2);
  float* xbuf   = (float*)alloc((size_t)NN * H * 4);
  float* agg    = (float*)alloc((size_t)NN * H * 4);
  u16*   xnb    = (u16*)  alloc((size_t)NN * H * 2);
  u16*   hbuf   = (u16*)  alloc((size_t)NN * H * 2);

  u16* l2Wt = wt;
  u16* lWt  = wt + (size_t)NL * 128 * 136;
  u16* l1Wt = wt + (size_t)2 * NL * 128 * 136;

  dim3 b256(256);
  int gE256 = (NE + 255) / 256;        // 2500
  int gNH   = (NN * H + 255) / 256;    // 10000
  int gES   = NE / 256;                // 2500
  int gG    = NN / 32;                 // 625
  int gM    = (NN + 63) / 64;          // 313
  int gTB   = 7 * (TBINS / 32);        // 896
  int gPW   = (3 * NL * 128 * 136 + 255) / 256;

  k_zero_i32<<<(NN + 255) / 256, b256, 0, stream>>>(counts, NN);
  k_hist<<<gE256, b256, 0, stream>>>(ei, counts);
  k_scan<<<1, 1024, 0, stream>>>(counts, cursor);
  k_place<<<gE256, b256, 0, stream>>>(ei, cursor, perm);
  k_edge<<<gE256, b256, 0, stream>>>(ei, perm, pos, srcS, dstS, tvS);
  k_tbuild<<<gTB, b256, 0, stream>>>(means, betas, npW, npb, W1, b1, W2, b2, tb);
  k_prepw2<<<gPW, b256, 0, stream>>>(l2W, lW, l1W, wt);
  k_embed<<<gNH, b256, 0, stream>>>(z, emb, nemb, xbuf, xnb, agg);

  // neighbor embedding scatter (table 0, self-mask on)
  k_es<<<gES, b256, 0, stream>>>(srcS, dstS, tvS, tb, xnb, agg, 1);
  k_combine<<<gG, b256, 0, stream>>>(xbuf, agg, cW, cb, l1W, xbuf, hbuf);

  for (int l = 0; l < NL; ++l) {
    k_es<<<gES, b256, 0, stream>>>(srcS, dstS, tvS,
                                   tb + (size_t)(1 + l) * TBINS * H,
                                   hbuf, agg, 0);
    const u16* l1Wnt = (l + 1 < NL) ? (l1Wt + (size_t)(l + 1) * 128 * 136) : nullptr;
    float* xo = (l == NL - 1) ? (float*)d_out : xbuf;
    k_gemmM<<<gM, b256, 0, stream>>>(agg, l2Wt + (size_t)l * 128 * 136, l2b + (size_t)l * H,
                                     lWt + (size_t)l * 128 * 136, lb + (size_t)l * H,
                                     xbuf, xo, l1Wnt, hbuf);
  }
}

// Round 15
// 683.214 us; speedup vs baseline: 5.1572x; 1.1539x over previous
//
#include <hip/hip_runtime.h>
#include <hip/hip_bf16.h>
#include <math.h>

#define NN 20000
#define NE 640000
#define H  128
#define RB 50
#define NL 6
#define TBINS 4096

typedef unsigned short u16;
typedef __attribute__((ext_vector_type(8))) short short8v;
typedef __attribute__((ext_vector_type(4))) float f32x4;

// gather permutation (h/xn/tables): col c -> slot (c&15)*8 + (c>>4)
__device__ __forceinline__ u16 f2b(float v) {
  unsigned x = __float_as_uint(v);
  unsigned r = (x + 0x7FFFu + ((x >> 16) & 1u)) >> 16;
  return (u16)r;
}
__device__ __forceinline__ float b2f(u16 u) {
  return __uint_as_float(((unsigned int)u) << 16);
}

// ---------------- sort machinery ----------------
__global__ void k_zero_i32(int* __restrict__ p, int n) {
  int i = blockIdx.x * blockDim.x + threadIdx.x;
  if (i < n) p[i] = 0;
}
__global__ void k_hist(const int* __restrict__ ei, int* __restrict__ counts) {
  int e = blockIdx.x * blockDim.x + threadIdx.x;
  if (e < NE) atomicAdd(&counts[ei[NE + e]], 1);
}
// fast single-block scan: 1024 threads x 20 serial elements
__global__ __launch_bounds__(1024) void k_scan(const int* __restrict__ counts,
                                               int* __restrict__ cursor) {
  __shared__ int tsum[1024];
  int tid = threadIdx.x;
  int base = tid * 20;
  int s = 0;
  #pragma unroll
  for (int j = 0; j < 20; ++j) {
    int i = base + j;
    s += (i < NN) ? counts[i] : 0;
  }
  tsum[tid] = s;
  __syncthreads();
  for (int off = 1; off < 1024; off <<= 1) {
    int t = (tid >= off) ? tsum[tid - off] : 0;
    __syncthreads();
    tsum[tid] += t;
    __syncthreads();
  }
  int run = (tid > 0) ? tsum[tid - 1] : 0;
  #pragma unroll
  for (int j = 0; j < 20; ++j) {
    int i = base + j;
    if (i < NN) { cursor[i] = run; run += counts[i]; }
  }
}
__global__ void k_place(const int* __restrict__ ei, int* __restrict__ cursor,
                        int* __restrict__ perm) {
  int e = blockIdx.x * blockDim.x + threadIdx.x;
  if (e < NE) {
    int d = ei[NE + e];
    int p = atomicAdd(&cursor[d], 1);
    perm[p] = e;
  }
}

// ---------------- edge precompute: sorted src/dst/tv only ----------------
__global__ void k_edge(const int* __restrict__ ei, const int* __restrict__ perm,
                       const float* __restrict__ pos,
                       int* __restrict__ srcS, int* __restrict__ dstS,
                       float* __restrict__ tvS) {
  int p = blockIdx.x * 256 + threadIdx.x;
  if (p >= NE) return;
  int e = perm[p];
  int s = ei[e], t = ei[NE + e];
  srcS[p] = s; dstS[p] = t;
  float dx = pos[3*s]   - pos[3*t];
  float dy = pos[3*s+1] - pos[3*t+1];
  float dz = pos[3*s+2] - pos[3*t+2];
  float d = sqrtf(dx*dx + dy*dy + dz*dz);
  tvS[p] = expf(-d);
}

// ---------------- filter tables: F_t(tv) in R^128, bf16, PERMUTED cols ----------------
__global__ __launch_bounds__(256) void k_tbuild(
    const float* __restrict__ means, const float* __restrict__ betas,
    const float* __restrict__ npW, const float* __restrict__ npb,
    const float* __restrict__ W1, const float* __restrict__ b1,
    const float* __restrict__ W2, const float* __restrict__ b2,
    u16* __restrict__ tb)
{
  int t  = blockIdx.x / (TBINS / 32);
  int j0 = (blockIdx.x % (TBINS / 32)) * 32;
  __shared__ float sAttr[32][52];
  __shared__ float sCut[32];
  __shared__ float sT[32][132];
  int tid = threadIdx.x;
  float tv0 = expf(-5.f);
  float dtv = (1.f - tv0) / (float)(TBINS - 1);
  for (int idx = tid; idx < 32 * RB; idx += 256) {
    int r = idx / RB, k = idx % RB;
    float tv = tv0 + (j0 + r) * dtv;
    float d = -logf(tv);
    float C = 0.5f * (cosf(d * 0.628318530717958647692f) + 1.f);
    if (d >= 5.f) C = 0.f;
    float diff = tv - means[k];
    sAttr[r][k] = C * expf(-betas[k] * diff * diff);
    if (k == 0) sCut[r] = C;
  }
  __syncthreads();
  int g = tid >> 5, c0 = (tid & 31) * 4, eb = g * 4;
  float acc[4][4];
  #pragma unroll
  for (int i = 0; i < 4; ++i)
    for (int j = 0; j < 4; ++j) acc[i][j] = 0.f;
  const float* Wa = (t == 0) ? npW : (W1 + (size_t)(t - 1) * RB * H);
  for (int k = 0; k < RB; ++k) {
    float4 wv = *(const float4*)&Wa[(size_t)k * H + c0];
    #pragma unroll
    for (int i = 0; i < 4; ++i) {
      float a = sAttr[eb + i][k];
      acc[i][0] += a * wv.x; acc[i][1] += a * wv.y;
      acc[i][2] += a * wv.z; acc[i][3] += a * wv.w;
    }
  }
  size_t obase = (size_t)t * TBINS * H;
  int pb = (c0 & 15) * 8 + (c0 >> 4);
  if (t == 0) {
    float4 b4 = *(const float4*)&npb[c0];
    float bvA[4] = {b4.x, b4.y, b4.z, b4.w};
    #pragma unroll
    for (int i = 0; i < 4; ++i) {
      float Cv = sCut[eb + i];
      size_t rb = obase + (size_t)(j0 + eb + i) * H;
      #pragma unroll
      for (int j = 0; j < 4; ++j)
        tb[rb + pb + 8 * j] = f2b((acc[i][j] + bvA[j]) * Cv);
    }
  } else {
    float4 b4 = *(const float4*)&b1[(size_t)(t - 1) * H + c0];
    float bvA[4] = {b4.x, b4.y, b4.z, b4.w};
    #pragma unroll
    for (int i = 0; i < 4; ++i) {
      #pragma unroll
      for (int j = 0; j < 4; ++j) {
        float v = acc[i][j] + bvA[j];
        sT[eb + i][c0 + j] = v / (1.f + __expf(-v));
      }
    }
    __syncthreads();
    #pragma unroll
    for (int i = 0; i < 4; ++i)
      for (int j = 0; j < 4; ++j) acc[i][j] = 0.f;
    const float* Wb = W2 + (size_t)(t - 1) * H * H;
    for (int k = 0; k < H; ++k) {
      float4 wv = *(const float4*)&Wb[(size_t)k * H + c0];
      #pragma unroll
      for (int i = 0; i < 4; ++i) {
        float a = sT[eb + i][k];
        acc[i][0] += a * wv.x; acc[i][1] += a * wv.y;
        acc[i][2] += a * wv.z; acc[i][3] += a * wv.w;
      }
    }
    float4 b24 = *(const float4*)&b2[(size_t)(t - 1) * H + c0];
    float bvB[4] = {b24.x, b24.y, b24.z, b24.w};
    #pragma unroll
    for (int i = 0; i < 4; ++i) {
      float Cv = sCut[eb + i];
      size_t rb = obase + (size_t)(j0 + eb + i) * H;
      #pragma unroll
      for (int j = 0; j < 4; ++j)
        tb[rb + pb + 8 * j] = f2b((acc[i][j] + bvB[j]) * Cv);
    }
  }
}

// ---------------- node-GEMM weight transpose to bf16 [n][k] stride 136 ----------------
__global__ void k_prepw2(const float* __restrict__ l2W, const float* __restrict__ lW,
                         const float* __restrict__ l1W, u16* __restrict__ wt) {
  int i = blockIdx.x * 256 + threadIdx.x;
  if (i >= 3 * NL * 128 * 136) return;
  int a = i / (NL * 128 * 136);
  int r = i % (NL * 128 * 136);
  int l = r / (128 * 136);
  int r2 = r % (128 * 136);
  int n = r2 / 136, k = r2 % 136;
  const float* src = (a == 0) ? l2W : (a == 1) ? lW : l1W;
  wt[i] = (k < H) ? f2b(src[(size_t)l * H * H + (size_t)k * H + n]) : (u16)0;
}

// x f32 natural; xn bf16 PERMUTED; agg (natural) zero-init
__global__ void k_embed(const int* __restrict__ z, const float* __restrict__ emb,
                        const float* __restrict__ nemb,
                        float* __restrict__ x, u16* __restrict__ xnb,
                        float* __restrict__ aggz) {
  int i = blockIdx.x * blockDim.x + threadIdx.x;
  if (i >= NN * H) return;
  int n = i >> 7, c = i & (H - 1);
  long o = (long)z[n] * H + c;
  x[i] = emb[o];
  xnb[(size_t)n * H + ((c & 15) * 8 + (c >> 4))] = f2b(nemb[o]);
  aggz[i] = 0.f;
}

// ---------------- edge scatter: 2 chains x depth-3 pipelined ----------------
// 16 lanes/edge (8 ch each); each 16-lane group walks 2 independent 16-edge runs
__global__ __launch_bounds__(256) void k_es(
    const int* __restrict__ srcS, const int* __restrict__ dstS,
    const float* __restrict__ tvS, const u16* __restrict__ tb,
    const u16* __restrict__ hsrc, float* __restrict__ agg, int maskSelf)
{
  int tid = threadIdx.x;
  int lane = tid & 63, wv = tid >> 6;
  int r16 = lane & 15, g4 = lane >> 4;
  int g16 = g4 * 16;
  long ebase = (long)blockIdx.x * 512 + wv * 128 + g4 * 32;
  int srcR_A = srcS[ebase + r16];
  int dstR_A = dstS[ebase + r16];
  float tvR_A = tvS[ebase + r16];
  int srcR_B = srcS[ebase + 16 + r16];
  int dstR_B = dstS[ebase + 16 + r16];
  float tvR_B = tvS[ebase + 16 + r16];
  float tv0 = expf(-5.f);
  float inv = (float)(TBINS - 1) / (1.f - tv0);
  float vsumA[8], vsumB[8];
  #pragma unroll
  for (int ct = 0; ct < 8; ++ct) { vsumA[ct] = 0.f; vsumB[ct] = 0.f; }
  int pdstA = -1, pdstB = -1;
#define DECLS(P) int P##_s, P##_d; float P##_w; short8v P##_hv, P##_lo, P##_hi;
  DECLS(A0) DECLS(A1) DECLS(A2) DECLS(B0) DECLS(B1) DECLS(B2)
#define ISSUE(P, R, ii) { \
    P##_s = __shfl(srcR_##R, g16 + (ii), 64); \
    P##_d = __shfl(dstR_##R, g16 + (ii), 64); \
    float tvv = __shfl(tvR_##R, g16 + (ii), 64); \
    P##_hv = *(const short8v*)&hsrc[(size_t)P##_s * H + r16 * 8]; \
    float u = fminf(fmaxf((tvv - tv0) * inv, 0.f), (float)(TBINS - 1) - 1e-3f); \
    int jj = (int)u; P##_w = u - (float)jj; \
    P##_lo = *(const short8v*)&tb[(size_t)jj * H + r16 * 8]; \
    P##_hi = *(const short8v*)&tb[(size_t)(jj + 1) * H + r16 * 8]; }
#define CONSUME(P, R) { \
    float m = (maskSelf && P##_s == P##_d) ? 0.f : 1.f; \
    if (P##_d != pdst##R) { \
      if (pdst##R >= 0) { \
        float* ap = agg + (size_t)pdst##R * H + r16; \
        _Pragma("unroll") \
        for (int ct = 0; ct < 8; ++ct) atomicAdd(ap + ct * 16, vsum##R[ct]); \
      } \
      _Pragma("unroll") \
      for (int ct = 0; ct < 8; ++ct) vsum##R[ct] = 0.f; \
      pdst##R = P##_d; \
    } \
    _Pragma("unroll") \
    for (int ct = 0; ct < 8; ++ct) { \
      float lo = b2f((u16)P##_lo[ct]); \
      float hi = b2f((u16)P##_hi[ct]); \
      vsum##R[ct] += (lo + P##_w * (hi - lo)) * m * b2f((u16)P##_hv[ct]); \
    } }
  ISSUE(A0, A, 0); ISSUE(B0, B, 0);
  ISSUE(A1, A, 1); ISSUE(B1, B, 1);
  ISSUE(A2, A, 2); ISSUE(B2, B, 2);
  #pragma unroll
  for (int i = 0; i < 16; ++i) {
    int ph = i % 3;
    if (ph == 0) {
      CONSUME(A0, A); if (i + 3 < 16) ISSUE(A0, A, i + 3);
      CONSUME(B0, B); if (i + 3 < 16) ISSUE(B0, B, i + 3);
    } else if (ph == 1) {
      CONSUME(A1, A); if (i + 3 < 16) ISSUE(A1, A, i + 3);
      CONSUME(B1, B); if (i + 3 < 16) ISSUE(B1, B, i + 3);
    } else {
      CONSUME(A2, A); if (i + 3 < 16) ISSUE(A2, A, i + 3);
      CONSUME(B2, B); if (i + 3 < 16) ISSUE(B2, B, i + 3);
    }
  }
#undef ISSUE
#undef CONSUME
#undef DECLS
  if (pdstA >= 0) {
    float* ap = agg + (size_t)pdstA * H + r16;
    #pragma unroll
    for (int ct = 0; ct < 8; ++ct) atomicAdd(ap + ct * 16, vsumA[ct]);
  }
  if (pdstB >= 0) {
    float* ap = agg + (size_t)pdstB * H + r16;
    #pragma unroll
    for (int ct = 0; ct < 8; ++ct) atomicAdd(ap + ct * 16, vsumB[ct]);
  }
}

// ---------------- combine: x = [x||agg]@cW + cb;  h0 = x@l1W0 (bf16 permuted) ----------------
__global__ __launch_bounds__(256) void k_combine(
    const float* __restrict__ xb, float* __restrict__ ag,
    const float* __restrict__ cW, const float* __restrict__ cb,
    const float* __restrict__ l1W0, float* __restrict__ xout,
    u16* __restrict__ hb)
{
  __shared__ float sX[32][132];
  __shared__ float sG[32][132];
  int tid = threadIdx.x;
  int n0 = blockIdx.x * 32;
  #pragma unroll
  for (int j = 0; j < 4; ++j) {
    int f4 = tid + j * 256;
    int r = f4 >> 5, c4 = f4 & 31;
    *(float4*)&sX[r][c4 * 4] = *(const float4*)&xb[(size_t)(n0 + r) * H + c4 * 4];
    *(float4*)&sG[r][c4 * 4] = *(const float4*)&ag[(size_t)(n0 + r) * H + c4 * 4];
    *(float4*)&ag[(size_t)(n0 + r) * H + c4 * 4] = make_float4(0.f, 0.f, 0.f, 0.f);
  }
  __syncthreads();
  int g = tid >> 5;
  int c0 = (tid & 31) * 4;
  int eb = g * 4;
  float acc[4][4];
  #pragma unroll
  for (int i = 0; i < 4; ++i)
    for (int j = 0; j < 4; ++j) acc[i][j] = 0.f;
  for (int k = 0; k < H; ++k) {
    float4 wv = *(const float4*)&cW[(size_t)k * H + c0];
    #pragma unroll
    for (int i = 0; i < 4; ++i) {
      float a = sX[eb + i][k];
      acc[i][0] += a * wv.x; acc[i][1] += a * wv.y;
      acc[i][2] += a * wv.z; acc[i][3] += a * wv.w;
    }
  }
  for (int k = 0; k < H; ++k) {
    float4 wv = *(const float4*)&cW[(size_t)(H + k) * H + c0];
    #pragma unroll
    for (int i = 0; i < 4; ++i) {
      float a = sG[eb + i][k];
      acc[i][0] += a * wv.x; acc[i][1] += a * wv.y;
      acc[i][2] += a * wv.z; acc[i][3] += a * wv.w;
    }
  }
  float4 bv = *(const float4*)&cb[c0];
  __syncthreads();
  #pragma unroll
  for (int i = 0; i < 4; ++i) {
    int n = n0 + eb + i;
    float o0 = acc[i][0] + bv.x, o1 = acc[i][1] + bv.y;
    float o2 = acc[i][2] + bv.z, o3 = acc[i][3] + bv.w;
    *(float4*)&xout[(size_t)n * H + c0] = make_float4(o0, o1, o2, o3);
    sX[eb + i][c0] = o0; sX[eb + i][c0+1] = o1;
    sX[eb + i][c0+2] = o2; sX[eb + i][c0+3] = o3;
  }
  __syncthreads();
  #pragma unroll
  for (int i = 0; i < 4; ++i)
    for (int j = 0; j < 4; ++j) acc[i][j] = 0.f;
  for (int k = 0; k < H; ++k) {
    float4 wv = *(const float4*)&l1W0[(size_t)k * H + c0];
    #pragma unroll
    for (int i = 0; i < 4; ++i) {
      float a = sX[eb + i][k];
      acc[i][0] += a * wv.x; acc[i][1] += a * wv.y;
      acc[i][2] += a * wv.z; acc[i][3] += a * wv.w;
    }
  }
  int pbase = (c0 & 15) * 8 + (c0 >> 4);
  #pragma unroll
  for (int i = 0; i < 4; ++i) {
    int n = n0 + eb + i;
    #pragma unroll
    for (int j = 0; j < 4; ++j)
      hb[(size_t)n * H + pbase + 8 * j] = f2b(acc[i][j]);
  }
}

// ---------------- MFMA node chain: x += silu(agg@W2+b2)@W3 + b3; hb = x@l1Wn ----------------
__global__ __launch_bounds__(256) void k_gemmM(
    float* __restrict__ A, const u16* __restrict__ W2t, const float* __restrict__ b2,
    const u16* __restrict__ W3t, const float* __restrict__ b3,
    const float* __restrict__ xin, float* __restrict__ xout,
    const u16* __restrict__ l1Wnt, u16* __restrict__ hb)
{
  __shared__ __align__(16) u16 sA[64 * 136];
  __shared__ __align__(16) u16 sT[64 * 136];
  int tid = threadIdx.x;
  int lane = tid & 63, wv = tid >> 6;
  int r16 = lane & 15, g4 = lane >> 4;
  int n0 = blockIdx.x * 64;
  #pragma unroll
  for (int j = 0; j < 8; ++j) {
    int f4 = tid + j * 256;
    int r = f4 >> 5, c4 = f4 & 31;
    int n = n0 + r;
    float4 v = make_float4(0.f, 0.f, 0.f, 0.f);
    if (n < NN) {
      v = *(const float4*)&A[(size_t)n * H + c4 * 4];
      *(float4*)&A[(size_t)n * H + c4 * 4] = make_float4(0.f, 0.f, 0.f, 0.f);
    }
    unsigned lo = (unsigned)f2b(v.x) | ((unsigned)f2b(v.y) << 16);
    unsigned hi = (unsigned)f2b(v.z) | ((unsigned)f2b(v.w) << 16);
    *(unsigned*)&sA[r * 136 + c4 * 4]     = lo;
    *(unsigned*)&sA[r * 136 + c4 * 4 + 2] = hi;
  }
  __syncthreads();
  int wrow = wv * 16;
  f32x4 acc[8];
  #pragma unroll
  for (int ct = 0; ct < 8; ++ct) acc[ct] = (f32x4){0.f, 0.f, 0.f, 0.f};
  #pragma unroll
  for (int kt = 0; kt < 4; ++kt) {
    short8v aF = *(const short8v*)&sA[(wrow + r16) * 136 + kt * 32 + g4 * 8];
    #pragma unroll
    for (int ct = 0; ct < 8; ++ct) {
      short8v bF = *(const short8v*)&W2t[(ct * 16 + r16) * 136 + kt * 32 + g4 * 8];
      acc[ct] = __builtin_amdgcn_mfma_f32_16x16x32_bf16(aF, bF, acc[ct], 0, 0, 0);
    }
  }
  #pragma unroll
  for (int ct = 0; ct < 8; ++ct) {
    float bb = b2[ct * 16 + r16];
    #pragma unroll
    for (int r = 0; r < 4; ++r) {
      float v = acc[ct][r] + bb;
      v = v / (1.f + __expf(-v));
      sT[(wrow + g4 * 4 + r) * 136 + ct * 16 + r16] = f2b(v);
    }
  }
  #pragma unroll
  for (int ct = 0; ct < 8; ++ct) acc[ct] = (f32x4){0.f, 0.f, 0.f, 0.f};
  #pragma unroll
  for (int kt = 0; kt < 4; ++kt) {
    short8v aF = *(const short8v*)&sT[(wrow + r16) * 136 + kt * 32 + g4 * 8];
    #pragma unroll
    for (int ct = 0; ct < 8; ++ct) {
      short8v bF = *(const short8v*)&W3t[(ct * 16 + r16) * 136 + kt * 32 + g4 * 8];
      acc[ct] = __builtin_amdgcn_mfma_f32_16x16x32_bf16(aF, bF, acc[ct], 0, 0, 0);
    }
  }
  #pragma unroll
  for (int ct = 0; ct < 8; ++ct) {
    float bb = b3[ct * 16 + r16];
    #pragma unroll
    for (int r = 0; r < 4; ++r) {
      int n = n0 + wrow + g4 * 4 + r;
      if (n < NN) {
        float o = acc[ct][r] + bb + xin[(size_t)n * H + ct * 16 + r16];
        xout[(size_t)n * H + ct * 16 + r16] = o;
        sA[(wrow + g4 * 4 + r) * 136 + ct * 16 + r16] = f2b(o);
      }
    }
  }
  if (!l1Wnt) return;
  #pragma unroll
  for (int ct = 0; ct < 8; ++ct) acc[ct] = (f32x4){0.f, 0.f, 0.f, 0.f};
  #pragma unroll
  for (int kt = 0; kt < 4; ++kt) {
    short8v aF = *(const short8v*)&sA[(wrow + r16) * 136 + kt * 32 + g4 * 8];
    #pragma unroll
    for (int ct = 0; ct < 8; ++ct) {
      short8v bF = *(const short8v*)&l1Wnt[(ct * 16 + r16) * 136 + kt * 32 + g4 * 8];
      acc[ct] = __builtin_amdgcn_mfma_f32_16x16x32_bf16(aF, bF, acc[ct], 0, 0, 0);
    }
  }
  #pragma unroll
  for (int r = 0; r < 4; ++r) {
    int n = n0 + wrow + g4 * 4 + r;
    if (n < NN) {
      short8v hv;
      #pragma unroll
      for (int ct = 0; ct < 8; ++ct) hv[ct] = (short)f2b(acc[ct][r]);
      *(short8v*)&hb[(size_t)n * H + r16 * 8] = hv;
    }
  }
}

// ---------------- launcher ----------------
extern "C" void kernel_launch(void* const* d_in, const int* in_sizes, int n_in,
                              void* d_out, int out_size, void* d_ws, size_t ws_size,
                              hipStream_t stream) {
  int bo = (n_in >= 4 && in_sizes[3] == NN) ? 0 : -1;  // batch present?
  const int*   z     = (const int*)d_in[0];
  const float* pos   = (const float*)d_in[1];
  const int*   ei    = (const int*)d_in[2];
  const float* emb   = (const float*)d_in[4 + bo];
  const float* nemb  = (const float*)d_in[5 + bo];
  const float* npW   = (const float*)d_in[6 + bo];
  const float* npb   = (const float*)d_in[7 + bo];
  const float* cW    = (const float*)d_in[8 + bo];
  const float* cb    = (const float*)d_in[9 + bo];
  const float* means = (const float*)d_in[10 + bo];
  const float* betas = (const float*)d_in[11 + bo];
  const float* W1    = (const float*)d_in[12 + bo];
  const float* b1    = (const float*)d_in[13 + bo];
  const float* W2    = (const float*)d_in[14 + bo];
  const float* b2    = (const float*)d_in[15 + bo];
  const float* l1W   = (const float*)d_in[16 + bo];
  const float* l2W   = (const float*)d_in[17 + bo];
  const float* l2b   = (const float*)d_in[18 + bo];
  const float* lW    = (const float*)d_in[19 + bo];
  const float* lb    = (const float*)d_in[20 + bo];

  char* w = (char*)d_ws;
  auto alloc = [&](size_t bytes) { char* p = w; w += (bytes + 255) & ~(size_t)255; return p; };
  int*   counts = (int*)  alloc((size_t)NN * 4);
  int*   cursor = (int*)  alloc((size_t)NN * 4);
  int*   perm   = (int*)  alloc((size_t)NE * 4);
  int*   srcS   = (int*)  alloc((size_t)NE * 4);
  int*   dstS   = (int*)  alloc((size_t)NE * 4);
  float* tvS    = (float*)alloc((size_t)NE * 4);
  u16*   tb     = (u16*)  alloc((size_t)7 * TBINS * H * 2);
  u16*   wt     = (u16*)  alloc((size_t)3 * NL * 128 * 136 * 2);
  float* xbuf   = (float*)alloc((size_t)NN * H * 4);
  float* agg    = (float*)alloc((size_t)NN * H * 4);
  u16*   xnb    = (u16*)  alloc((size_t)NN * H * 2);
  u16*   hbuf   = (u16*)  alloc((size_t)NN * H * 2);

  u16* l2Wt = wt;
  u16* lWt  = wt + (size_t)NL * 128 * 136;
  u16* l1Wt = wt + (size_t)2 * NL * 128 * 136;

  dim3 b256(256);
  int gE256 = (NE + 255) / 256;        // 2500
  int gNH   = (NN * H + 255) / 256;    // 10000
  int gES   = NE / 512;                // 1250
  int gG    = NN / 32;                 // 625
  int gM    = (NN + 63) / 64;          // 313
  int gTB   = 7 * (TBINS / 32);        // 896
  int gPW   = (3 * NL * 128 * 136 + 255) / 256;

  k_zero_i32<<<(NN + 255) / 256, b256, 0, stream>>>(counts, NN);
  k_hist<<<gE256, b256, 0, stream>>>(ei, counts);
  k_scan<<<1, 1024, 0, stream>>>(counts, cursor);
  k_place<<<gE256, b256, 0, stream>>>(ei, cursor, perm);
  k_edge<<<gE256, b256, 0, stream>>>(ei, perm, pos, srcS, dstS, tvS);
  k_tbuild<<<gTB, b256, 0, stream>>>(means, betas, npW, npb, W1, b1, W2, b2, tb);
  k_prepw2<<<gPW, b256, 0, stream>>>(l2W, lW, l1W, wt);
  k_embed<<<gNH, b256, 0, stream>>>(z, emb, nemb, xbuf, xnb, agg);

  // neighbor embedding scatter (table 0, self-mask on)
  k_es<<<gES, b256, 0, stream>>>(srcS, dstS, tvS, tb, xnb, agg, 1);
  k_combine<<<gG, b256, 0, stream>>>(xbuf, agg, cW, cb, l1W, xbuf, hbuf);

  for (int l = 0; l < NL; ++l) {
    k_es<<<gES, b256, 0, stream>>>(srcS, dstS, tvS,
                                   tb + (size_t)(1 + l) * TBINS * H,
                                   hbuf, agg, 0);
    const u16* l1Wnt = (l + 1 < NL) ? (l1Wt + (size_t)(l + 1) * 128 * 136) : nullptr;
    float* xo = (l == NL - 1) ? (float*)d_out : xbuf;
    k_gemmM<<<gM, b256, 0, stream>>>(agg, l2Wt + (size_t)l * 128 * 136, l2b + (size_t)l * H,
                                     lWt + (size_t)l * 128 * 136, lb + (size_t)l * H,
                                     xbuf, xo, l1Wnt, hbuf);
  }
}

// Round 16
// 674.881 us; speedup vs baseline: 5.2208x; 1.0123x over previous
//
#include <hip/hip_runtime.h>
#include <hip/hip_bf16.h>
#include <math.h>

#define NN 20000
#define NE 640000
#define H  128
#define RB 50
#define NL 6
#define TBINS 4096

typedef unsigned short u16;
typedef __attribute__((ext_vector_type(8))) short short8v;
typedef __attribute__((ext_vector_type(4))) float f32x4;

// gather permutation (h/xn/tables): col c -> slot (c&15)*8 + (c>>4)
__device__ __forceinline__ u16 f2b(float v) {
  unsigned x = __float_as_uint(v);
  unsigned r = (x + 0x7FFFu + ((x >> 16) & 1u)) >> 16;
  return (u16)r;
}
__device__ __forceinline__ float b2f(u16 u) {
  return __uint_as_float(((unsigned int)u) << 16);
}

// ---------------- sort machinery ----------------
__global__ void k_zero_i32(int* __restrict__ p, int n) {
  int i = blockIdx.x * blockDim.x + threadIdx.x;
  if (i < n) p[i] = 0;
}
__global__ void k_hist(const int* __restrict__ ei, int* __restrict__ counts) {
  int e = blockIdx.x * blockDim.x + threadIdx.x;
  if (e < NE) atomicAdd(&counts[ei[NE + e]], 1);
}
// fast single-block scan: 1024 threads x 20 serial elements
__global__ __launch_bounds__(1024) void k_scan(const int* __restrict__ counts,
                                               int* __restrict__ cursor) {
  __shared__ int tsum[1024];
  int tid = threadIdx.x;
  int base = tid * 20;
  int s = 0;
  #pragma unroll
  for (int j = 0; j < 20; ++j) {
    int i = base + j;
    s += (i < NN) ? counts[i] : 0;
  }
  tsum[tid] = s;
  __syncthreads();
  for (int off = 1; off < 1024; off <<= 1) {
    int t = (tid >= off) ? tsum[tid - off] : 0;
    __syncthreads();
    tsum[tid] += t;
    __syncthreads();
  }
  int run = (tid > 0) ? tsum[tid - 1] : 0;
  #pragma unroll
  for (int j = 0; j < 20; ++j) {
    int i = base + j;
    if (i < NN) { cursor[i] = run; run += counts[i]; }
  }
}
__global__ void k_place(const int* __restrict__ ei, int* __restrict__ cursor,
                        int* __restrict__ perm) {
  int e = blockIdx.x * blockDim.x + threadIdx.x;
  if (e < NE) {
    int d = ei[NE + e];
    int p = atomicAdd(&cursor[d], 1);
    perm[p] = e;
  }
}

// ---------------- edge precompute: sorted src/tv only ----------------
__global__ void k_edge(const int* __restrict__ ei, const int* __restrict__ perm,
                       const float* __restrict__ pos,
                       int* __restrict__ srcS, float* __restrict__ tvS) {
  int p = blockIdx.x * 256 + threadIdx.x;
  if (p >= NE) return;
  int e = perm[p];
  int s = ei[e], t = ei[NE + e];
  srcS[p] = s;
  float dx = pos[3*s]   - pos[3*t];
  float dy = pos[3*s+1] - pos[3*t+1];
  float dz = pos[3*s+2] - pos[3*t+2];
  float d = sqrtf(dx*dx + dy*dy + dz*dz);
  tvS[p] = expf(-d);
}

// ---------------- filter tables: F_t(tv) in R^128, bf16, PERMUTED cols ----------------
__global__ __launch_bounds__(256) void k_tbuild(
    const float* __restrict__ means, const float* __restrict__ betas,
    const float* __restrict__ npW, const float* __restrict__ npb,
    const float* __restrict__ W1, const float* __restrict__ b1,
    const float* __restrict__ W2, const float* __restrict__ b2,
    u16* __restrict__ tb)
{
  int t  = blockIdx.x / (TBINS / 32);
  int j0 = (blockIdx.x % (TBINS / 32)) * 32;
  __shared__ float sAttr[32][52];
  __shared__ float sCut[32];
  __shared__ float sT[32][132];
  int tid = threadIdx.x;
  float tv0 = expf(-5.f);
  float dtv = (1.f - tv0) / (float)(TBINS - 1);
  for (int idx = tid; idx < 32 * RB; idx += 256) {
    int r = idx / RB, k = idx % RB;
    float tv = tv0 + (j0 + r) * dtv;
    float d = -logf(tv);
    float C = 0.5f * (cosf(d * 0.628318530717958647692f) + 1.f);
    if (d >= 5.f) C = 0.f;
    float diff = tv - means[k];
    sAttr[r][k] = C * expf(-betas[k] * diff * diff);
    if (k == 0) sCut[r] = C;
  }
  __syncthreads();
  int g = tid >> 5, c0 = (tid & 31) * 4, eb = g * 4;
  float acc[4][4];
  #pragma unroll
  for (int i = 0; i < 4; ++i)
    for (int j = 0; j < 4; ++j) acc[i][j] = 0.f;
  const float* Wa = (t == 0) ? npW : (W1 + (size_t)(t - 1) * RB * H);
  for (int k = 0; k < RB; ++k) {
    float4 wv = *(const float4*)&Wa[(size_t)k * H + c0];
    #pragma unroll
    for (int i = 0; i < 4; ++i) {
      float a = sAttr[eb + i][k];
      acc[i][0] += a * wv.x; acc[i][1] += a * wv.y;
      acc[i][2] += a * wv.z; acc[i][3] += a * wv.w;
    }
  }
  size_t obase = (size_t)t * TBINS * H;
  int pb = (c0 & 15) * 8 + (c0 >> 4);
  if (t == 0) {
    float4 b4 = *(const float4*)&npb[c0];
    float bvA[4] = {b4.x, b4.y, b4.z, b4.w};
    #pragma unroll
    for (int i = 0; i < 4; ++i) {
      float Cv = sCut[eb + i];
      size_t rb = obase + (size_t)(j0 + eb + i) * H;
      #pragma unroll
      for (int j = 0; j < 4; ++j)
        tb[rb + pb + 8 * j] = f2b((acc[i][j] + bvA[j]) * Cv);
    }
  } else {
    float4 b4 = *(const float4*)&b1[(size_t)(t - 1) * H + c0];
    float bvA[4] = {b4.x, b4.y, b4.z, b4.w};
    #pragma unroll
    for (int i = 0; i < 4; ++i) {
      #pragma unroll
      for (int j = 0; j < 4; ++j) {
        float v = acc[i][j] + bvA[j];
        sT[eb + i][c0 + j] = v / (1.f + __expf(-v));
      }
    }
    __syncthreads();
    #pragma unroll
    for (int i = 0; i < 4; ++i)
      for (int j = 0; j < 4; ++j) acc[i][j] = 0.f;
    const float* Wb = W2 + (size_t)(t - 1) * H * H;
    for (int k = 0; k < H; ++k) {
      float4 wv = *(const float4*)&Wb[(size_t)k * H + c0];
      #pragma unroll
      for (int i = 0; i < 4; ++i) {
        float a = sT[eb + i][k];
        acc[i][0] += a * wv.x; acc[i][1] += a * wv.y;
        acc[i][2] += a * wv.z; acc[i][3] += a * wv.w;
      }
    }
    float4 b24 = *(const float4*)&b2[(size_t)(t - 1) * H + c0];
    float bvB[4] = {b24.x, b24.y, b24.z, b24.w};
    #pragma unroll
    for (int i = 0; i < 4; ++i) {
      float Cv = sCut[eb + i];
      size_t rb = obase + (size_t)(j0 + eb + i) * H;
      #pragma unroll
      for (int j = 0; j < 4; ++j)
        tb[rb + pb + 8 * j] = f2b((acc[i][j] + bvB[j]) * Cv);
    }
  }
}

// ---------------- weight transpose to bf16 [n][k] stride 136 ----------------
// layout in wt: l2Wt[6], lWt[6], l1Wt[6], cWt0, cWt1  (each 128x136)
#define WBLK (128 * 136)
__global__ void k_prepw2(const float* __restrict__ l2W, const float* __restrict__ lW,
                         const float* __restrict__ l1W, const float* __restrict__ cW,
                         u16* __restrict__ wt) {
  int i = blockIdx.x * 256 + threadIdx.x;
  if (i >= (3 * NL + 2) * WBLK) return;
  if (i < 3 * NL * WBLK) {
    int a = i / (NL * WBLK);
    int r = i % (NL * WBLK);
    int l = r / WBLK;
    int r2 = r % WBLK;
    int n = r2 / 136, k = r2 % 136;
    const float* src = (a == 0) ? l2W : (a == 1) ? lW : l1W;
    wt[i] = (k < H) ? f2b(src[(size_t)l * H * H + (size_t)k * H + n]) : (u16)0;
  } else {
    int j = i - 3 * NL * WBLK;
    int which = j / WBLK;
    int r2 = j % WBLK;
    int n = r2 / 136, k = r2 % 136;
    wt[i] = (k < H) ? f2b(cW[(size_t)(which * 128 + k) * H + n]) : (u16)0;
  }
}

// x f32 natural; xn bf16 PERMUTED
__global__ void k_embed(const int* __restrict__ z, const float* __restrict__ emb,
                        const float* __restrict__ nemb,
                        float* __restrict__ x, u16* __restrict__ xnb) {
  int i = blockIdx.x * blockDim.x + threadIdx.x;
  if (i >= NN * H) return;
  int n = i >> 7, c = i & (H - 1);
  long o = (long)z[n] * H + c;
  x[i] = emb[o];
  xnb[(size_t)n * H + ((c & 15) * 8 + (c >> 4))] = f2b(nemb[o]);
}

// ---------------- dst-owned edge scatter: no atomics, plain stores ----------------
// one 16-lane group per node; depth-3 pipelined walk over its contiguous edge range
__global__ __launch_bounds__(256) void k_eso(
    const int* __restrict__ counts, const int* __restrict__ cursor,
    const int* __restrict__ srcS, const float* __restrict__ tvS,
    const u16* __restrict__ tb, const u16* __restrict__ hsrc,
    float* __restrict__ agg, int maskSelf)
{
  int tid = threadIdx.x;
  int n = blockIdx.x * 16 + (tid >> 4);
  int r16 = tid & 15;
  int cnt = counts[n];
  long e0 = (long)cursor[n] - cnt;   // cursor = end after k_place
  float tv0 = expf(-5.f);
  float inv = (float)(TBINS - 1) / (1.f - tv0);
  float vsum[8];
  #pragma unroll
  for (int ct = 0; ct < 8; ++ct) vsum[ct] = 0.f;
  int P0_s = 0, P1_s = 0, P2_s = 0;
  float P0_w = 0.f, P1_w = 0.f, P2_w = 0.f;
  short8v P0_hv, P0_lo, P0_hi, P1_hv, P1_lo, P1_hi, P2_hv, P2_lo, P2_hi;
#define ISSUE(P, ii) { int _i = (ii); if (_i < cnt) { \
    long e = e0 + _i; \
    P##_s = srcS[e]; float tvv = tvS[e]; \
    P##_hv = *(const short8v*)&hsrc[(size_t)P##_s * H + r16 * 8]; \
    float u = fminf(fmaxf((tvv - tv0) * inv, 0.f), (float)(TBINS - 1) - 1e-3f); \
    int jj = (int)u; P##_w = u - (float)jj; \
    P##_lo = *(const short8v*)&tb[(size_t)jj * H + r16 * 8]; \
    P##_hi = *(const short8v*)&tb[(size_t)(jj + 1) * H + r16 * 8]; } }
#define CONSUME(P) { \
    float m = (maskSelf && P##_s == n) ? 0.f : 1.f; \
    _Pragma("unroll") \
    for (int ct = 0; ct < 8; ++ct) { \
      float lo = b2f((u16)P##_lo[ct]); \
      float hi = b2f((u16)P##_hi[ct]); \
      vsum[ct] += (lo + P##_w * (hi - lo)) * m * b2f((u16)P##_hv[ct]); \
    } }
  ISSUE(P0, 0); ISSUE(P1, 1); ISSUE(P2, 2);
  for (int i = 0; i < cnt; i += 3) {
    CONSUME(P0); ISSUE(P0, i + 3);
    if (i + 1 < cnt) { CONSUME(P1); ISSUE(P1, i + 4); }
    if (i + 2 < cnt) { CONSUME(P2); ISSUE(P2, i + 5); }
  }
#undef ISSUE
#undef CONSUME
  float* ap = agg + (size_t)n * H + r16;
  #pragma unroll
  for (int ct = 0; ct < 8; ++ct) ap[ct * 16] = vsum[ct];
}

// ---------------- MFMA combine: x = [x||agg]@cW + cb; h0 = x@l1W0 ----------------
__global__ __launch_bounds__(256) void k_combineM(
    const float* __restrict__ xb, const float* __restrict__ ag,
    const u16* __restrict__ cWt0, const u16* __restrict__ cWt1,
    const float* __restrict__ cb, const u16* __restrict__ l1W0t,
    float* __restrict__ xout, u16* __restrict__ hb)
{
  __shared__ __align__(16) u16 sX[64 * 136];
  __shared__ __align__(16) u16 sG[64 * 136];
  int tid = threadIdx.x;
  int lane = tid & 63, wv = tid >> 6;
  int r16 = lane & 15, g4 = lane >> 4;
  int n0 = blockIdx.x * 64;
  #pragma unroll
  for (int j = 0; j < 8; ++j) {
    int f4 = tid + j * 256;
    int r = f4 >> 5, c4 = f4 & 31;
    int n = n0 + r;
    float4 vx = make_float4(0.f, 0.f, 0.f, 0.f);
    float4 vg = make_float4(0.f, 0.f, 0.f, 0.f);
    if (n < NN) {
      vx = *(const float4*)&xb[(size_t)n * H + c4 * 4];
      vg = *(const float4*)&ag[(size_t)n * H + c4 * 4];
    }
    *(unsigned*)&sX[r * 136 + c4 * 4]     = (unsigned)f2b(vx.x) | ((unsigned)f2b(vx.y) << 16);
    *(unsigned*)&sX[r * 136 + c4 * 4 + 2] = (unsigned)f2b(vx.z) | ((unsigned)f2b(vx.w) << 16);
    *(unsigned*)&sG[r * 136 + c4 * 4]     = (unsigned)f2b(vg.x) | ((unsigned)f2b(vg.y) << 16);
    *(unsigned*)&sG[r * 136 + c4 * 4 + 2] = (unsigned)f2b(vg.z) | ((unsigned)f2b(vg.w) << 16);
  }
  __syncthreads();
  int wrow = wv * 16;
  f32x4 acc[8];
  #pragma unroll
  for (int ct = 0; ct < 8; ++ct) acc[ct] = (f32x4){0.f, 0.f, 0.f, 0.f};
  #pragma unroll
  for (int kt = 0; kt < 4; ++kt) {
    short8v aF = *(const short8v*)&sX[(wrow + r16) * 136 + kt * 32 + g4 * 8];
    #pragma unroll
    for (int ct = 0; ct < 8; ++ct) {
      short8v bF = *(const short8v*)&cWt0[(ct * 16 + r16) * 136 + kt * 32 + g4 * 8];
      acc[ct] = __builtin_amdgcn_mfma_f32_16x16x32_bf16(aF, bF, acc[ct], 0, 0, 0);
    }
  }
  #pragma unroll
  for (int kt = 0; kt < 4; ++kt) {
    short8v aF = *(const short8v*)&sG[(wrow + r16) * 136 + kt * 32 + g4 * 8];
    #pragma unroll
    for (int ct = 0; ct < 8; ++ct) {
      short8v bF = *(const short8v*)&cWt1[(ct * 16 + r16) * 136 + kt * 32 + g4 * 8];
      acc[ct] = __builtin_amdgcn_mfma_f32_16x16x32_bf16(aF, bF, acc[ct], 0, 0, 0);
    }
  }
  #pragma unroll
  for (int ct = 0; ct < 8; ++ct) {
    float bb = cb[ct * 16 + r16];
    #pragma unroll
    for (int r = 0; r < 4; ++r) {
      int n = n0 + wrow + g4 * 4 + r;
      if (n < NN) {
        float o = acc[ct][r] + bb;
        xout[(size_t)n * H + ct * 16 + r16] = o;
        sX[(wrow + g4 * 4 + r) * 136 + ct * 16 + r16] = f2b(o);
      }
    }
  }
  // GEMM3: h0 = xc @ l1W0 (wave-local rows; no barrier needed)
  #pragma unroll
  for (int ct = 0; ct < 8; ++ct) acc[ct] = (f32x4){0.f, 0.f, 0.f, 0.f};
  #pragma unroll
  for (int kt = 0; kt < 4; ++kt) {
    short8v aF = *(const short8v*)&sX[(wrow + r16) * 136 + kt * 32 + g4 * 8];
    #pragma unroll
    for (int ct = 0; ct < 8; ++ct) {
      short8v bF = *(const short8v*)&l1W0t[(ct * 16 + r16) * 136 + kt * 32 + g4 * 8];
      acc[ct] = __builtin_amdgcn_mfma_f32_16x16x32_bf16(aF, bF, acc[ct], 0, 0, 0);
    }
  }
  #pragma unroll
  for (int r = 0; r < 4; ++r) {
    int n = n0 + wrow + g4 * 4 + r;
    if (n < NN) {
      short8v hv;
      #pragma unroll
      for (int ct = 0; ct < 8; ++ct) hv[ct] = (short)f2b(acc[ct][r]);
      *(short8v*)&hb[(size_t)n * H + r16 * 8] = hv;
    }
  }
}

// ---------------- MFMA node chain: x += silu(agg@W2+b2)@W3 + b3; hb = x@l1Wn ----------------
__global__ __launch_bounds__(256) void k_gemmM(
    const float* __restrict__ A, const u16* __restrict__ W2t, const float* __restrict__ b2,
    const u16* __restrict__ W3t, const float* __restrict__ b3,
    const float* __restrict__ xin, float* __restrict__ xout,
    const u16* __restrict__ l1Wnt, u16* __restrict__ hb)
{
  __shared__ __align__(16) u16 sA[64 * 136];
  __shared__ __align__(16) u16 sT[64 * 136];
  int tid = threadIdx.x;
  int lane = tid & 63, wv = tid >> 6;
  int r16 = lane & 15, g4 = lane >> 4;
  int n0 = blockIdx.x * 64;
  #pragma unroll
  for (int j = 0; j < 8; ++j) {
    int f4 = tid + j * 256;
    int r = f4 >> 5, c4 = f4 & 31;
    int n = n0 + r;
    float4 v = make_float4(0.f, 0.f, 0.f, 0.f);
    if (n < NN) v = *(const float4*)&A[(size_t)n * H + c4 * 4];
    *(unsigned*)&sA[r * 136 + c4 * 4]     = (unsigned)f2b(v.x) | ((unsigned)f2b(v.y) << 16);
    *(unsigned*)&sA[r * 136 + c4 * 4 + 2] = (unsigned)f2b(v.z) | ((unsigned)f2b(v.w) << 16);
  }
  __syncthreads();
  int wrow = wv * 16;
  f32x4 acc[8];
  #pragma unroll
  for (int ct = 0; ct < 8; ++ct) acc[ct] = (f32x4){0.f, 0.f, 0.f, 0.f};
  #pragma unroll
  for (int kt = 0; kt < 4; ++kt) {
    short8v aF = *(const short8v*)&sA[(wrow + r16) * 136 + kt * 32 + g4 * 8];
    #pragma unroll
    for (int ct = 0; ct < 8; ++ct) {
      short8v bF = *(const short8v*)&W2t[(ct * 16 + r16) * 136 + kt * 32 + g4 * 8];
      acc[ct] = __builtin_amdgcn_mfma_f32_16x16x32_bf16(aF, bF, acc[ct], 0, 0, 0);
    }
  }
  #pragma unroll
  for (int ct = 0; ct < 8; ++ct) {
    float bb = b2[ct * 16 + r16];
    #pragma unroll
    for (int r = 0; r < 4; ++r) {
      float v = acc[ct][r] + bb;
      v = v / (1.f + __expf(-v));
      sT[(wrow + g4 * 4 + r) * 136 + ct * 16 + r16] = f2b(v);
    }
  }
  #pragma unroll
  for (int ct = 0; ct < 8; ++ct) acc[ct] = (f32x4){0.f, 0.f, 0.f, 0.f};
  #pragma unroll
  for (int kt = 0; kt < 4; ++kt) {
    short8v aF = *(const short8v*)&sT[(wrow + r16) * 136 + kt * 32 + g4 * 8];
    #pragma unroll
    for (int ct = 0; ct < 8; ++ct) {
      short8v bF = *(const short8v*)&W3t[(ct * 16 + r16) * 136 + kt * 32 + g4 * 8];
      acc[ct] = __builtin_amdgcn_mfma_f32_16x16x32_bf16(aF, bF, acc[ct], 0, 0, 0);
    }
  }
  #pragma unroll
  for (int ct = 0; ct < 8; ++ct) {
    float bb = b3[ct * 16 + r16];
    #pragma unroll
    for (int r = 0; r < 4; ++r) {
      int n = n0 + wrow + g4 * 4 + r;
      if (n < NN) {
        float o = acc[ct][r] + bb + xin[(size_t)n * H + ct * 16 + r16];
        xout[(size_t)n * H + ct * 16 + r16] = o;
        sA[(wrow + g4 * 4 + r) * 136 + ct * 16 + r16] = f2b(o);
      }
    }
  }
  if (!l1Wnt) return;
  #pragma unroll
  for (int ct = 0; ct < 8; ++ct) acc[ct] = (f32x4){0.f, 0.f, 0.f, 0.f};
  #pragma unroll
  for (int kt = 0; kt < 4; ++kt) {
    short8v aF = *(const short8v*)&sA[(wrow + r16) * 136 + kt * 32 + g4 * 8];
    #pragma unroll
    for (int ct = 0; ct < 8; ++ct) {
      short8v bF = *(const short8v*)&l1Wnt[(ct * 16 + r16) * 136 + kt * 32 + g4 * 8];
      acc[ct] = __builtin_amdgcn_mfma_f32_16x16x32_bf16(aF, bF, acc[ct], 0, 0, 0);
    }
  }
  #pragma unroll
  for (int r = 0; r < 4; ++r) {
    int n = n0 + wrow + g4 * 4 + r;
    if (n < NN) {
      short8v hv;
      #pragma unroll
      for (int ct = 0; ct < 8; ++ct) hv[ct] = (short)f2b(acc[ct][r]);
      *(short8v*)&hb[(size_t)n * H + r16 * 8] = hv;
    }
  }
}

// ---------------- launcher ----------------
extern "C" void kernel_launch(void* const* d_in, const int* in_sizes, int n_in,
                              void* d_out, int out_size, void* d_ws, size_t ws_size,
                              hipStream_t stream) {
  int bo = (n_in >= 4 && in_sizes[3] == NN) ? 0 : -1;  // batch present?
  const int*   z     = (const int*)d_in[0];
  const float* pos   = (const float*)d_in[1];
  const int*   ei    = (const int*)d_in[2];
  const float* emb   = (const float*)d_in[4 + bo];
  const float* nemb  = (const float*)d_in[5 + bo];
  const float* npW   = (const float*)d_in[6 + bo];
  const float* npb   = (const float*)d_in[7 + bo];
  const float* cW    = (const float*)d_in[8 + bo];
  const float* cb    = (const float*)d_in[9 + bo];
  const float* means = (const float*)d_in[10 + bo];
  const float* betas = (const float*)d_in[11 + bo];
  const float* W1    = (const float*)d_in[12 + bo];
  const float* b1    = (const float*)d_in[13 + bo];
  const float* W2    = (const float*)d_in[14 + bo];
  const float* b2    = (const float*)d_in[15 + bo];
  const float* l1W   = (const float*)d_in[16 + bo];
  const float* l2W   = (const float*)d_in[17 + bo];
  const float* l2b   = (const float*)d_in[18 + bo];
  const float* lW    = (const float*)d_in[19 + bo];
  const float* lb    = (const float*)d_in[20 + bo];

  char* w = (char*)d_ws;
  auto alloc = [&](size_t bytes) { char* p = w; w += (bytes + 255) & ~(size_t)255; return p; };
  int*   counts = (int*)  alloc((size_t)NN * 4);
  int*   cursor = (int*)  alloc((size_t)NN * 4);
  int*   perm   = (int*)  alloc((size_t)NE * 4);
  int*   srcS   = (int*)  alloc((size_t)NE * 4);
  float* tvS    = (float*)alloc((size_t)NE * 4);
  u16*   tb     = (u16*)  alloc((size_t)7 * TBINS * H * 2);
  u16*   wt     = (u16*)  alloc((size_t)(3 * NL + 2) * WBLK * 2);
  float* xbuf   = (float*)alloc((size_t)NN * H * 4);
  float* agg    = (float*)alloc((size_t)NN * H * 4);
  u16*   xnb    = (u16*)  alloc((size_t)NN * H * 2);
  u16*   hbuf   = (u16*)  alloc((size_t)NN * H * 2);

  u16* l2Wt = wt;
  u16* lWt  = wt + (size_t)NL * WBLK;
  u16* l1Wt = wt + (size_t)2 * NL * WBLK;
  u16* cWt0 = wt + (size_t)3 * NL * WBLK;
  u16* cWt1 = cWt0 + WBLK;

  dim3 b256(256);
  int gE256 = (NE + 255) / 256;        // 2500
  int gNH   = (NN * H + 255) / 256;    // 10000
  int gESO  = NN / 16;                 // 1250
  int gM    = (NN + 63) / 64;          // 313
  int gTB   = 7 * (TBINS / 32);        // 896
  int gPW   = ((3 * NL + 2) * WBLK + 255) / 256;

  k_zero_i32<<<(NN + 255) / 256, b256, 0, stream>>>(counts, NN);
  k_hist<<<gE256, b256, 0, stream>>>(ei, counts);
  k_scan<<<1, 1024, 0, stream>>>(counts, cursor);
  k_place<<<gE256, b256, 0, stream>>>(ei, cursor, perm);
  k_edge<<<gE256, b256, 0, stream>>>(ei, perm, pos, srcS, tvS);
  k_tbuild<<<gTB, b256, 0, stream>>>(means, betas, npW, npb, W1, b1, W2, b2, tb);
  k_prepw2<<<gPW, b256, 0, stream>>>(l2W, lW, l1W, cW, wt);
  k_embed<<<gNH, b256, 0, stream>>>(z, emb, nemb, xbuf, xnb);

  // neighbor embedding (table 0, self-mask on); agg fully written, no zeroing
  k_eso<<<gESO, b256, 0, stream>>>(counts, cursor, srcS, tvS, tb, xnb, agg, 1);
  k_combineM<<<gM, b256, 0, stream>>>(xbuf, agg, cWt0, cWt1, cb, l1Wt, xbuf, hbuf);

  for (int l = 0; l < NL; ++l) {
    k_eso<<<gESO, b256, 0, stream>>>(counts, cursor, srcS, tvS,
                                     tb + (size_t)(1 + l) * TBINS * H,
                                     hbuf, agg, 0);
    const u16* l1Wnt = (l + 1 < NL) ? (l1Wt + (size_t)(l + 1) * WBLK) : nullptr;
    float* xo = (l == NL - 1) ? (float*)d_out : xbuf;
    k_gemmM<<<gM, b256, 0, stream>>>(agg, l2Wt + (size_t)l * WBLK, l2b + (size_t)l * H,
                                     lWt + (size_t)l * WBLK, lb + (size_t)l * H,
                                     xbuf, xo, l1Wnt, hbuf);
  }
}